// Round 16
// baseline (761.183 us; speedup 1.0000x reference)
//
#include <hip/hip_runtime.h>

#define N_NODES 50000
#define N_EDGES 800000
#define HDIM    128
#define NBATCH  64
#define NCLS    3
#define KSEL    (N_NODES/2)
#define MMB_ROWS 64
#define TK_BLOCKS 512
#define POOL_BLOCKS 256
#define POOL_CHUNK  ((KSEL + POOL_BLOCKS - 1) / POOL_BLOCKS)
#define NBUCK ((N_NODES + 127) >> 7)
#define EPB   2048
#define S1_BLOCKS ((N_EDGES + EPB - 1) / EPB)
#define SEG_CAP 4096

typedef unsigned long long u64;
typedef unsigned int u32;
typedef unsigned short ushort_t;
typedef _Float16 half8 __attribute__((ext_vector_type(8)));
typedef float floatx4 __attribute__((ext_vector_type(4)));

struct SelState { u64 prefix; int krem; int cnt; };

__device__ __forceinline__ float h2f(ushort_t u) {
    _Float16 h = *(_Float16*)&u;
    return (float)h;
}

__global__ void init_pnorm_k(const float* __restrict__ p, float* __restrict__ pn,
        SelState* st) {
    __shared__ float red[HDIM];
    int t = threadIdx.x;
    float v = p[t];
    red[t] = v * v;
    __syncthreads();
    for (int s = HDIM/2; s > 0; s >>= 1) {
        if (t < s) red[t] += red[t+s];
        __syncthreads();
    }
    pn[t] = v / sqrtf(red[0]);
    if (t == 0) { st->prefix = 0ull; st->krem = KSEL; st->cnt = 0; }
}

__global__ void deg_full_k(const int* __restrict__ ei, int* __restrict__ degi) {
    int e = blockIdx.x * blockDim.x + threadIdx.x;
    if (e >= N_EDGES) return;
    int2 ed = ((const int2*)ei)[e];
    atomicAdd(&degi[ed.y], 1);
}

__global__ __launch_bounds__(256) void scan12_k(const int* __restrict__ degi,
        int* __restrict__ bsum, int* __restrict__ boff, float* __restrict__ dinv,
        int* __restrict__ rowptr, int n, int nb, int* done) {
    __shared__ int sh[256];
    __shared__ int lastf;
    int t = threadIdx.x;
    int i = blockIdx.x * 256 + t;
    int d = (i < n) ? degi[i] : 0;
    if (i < n) dinv[i] = rsqrtf((float)d + 1.0f);
    sh[t] = d;
    __syncthreads();
    for (int s = 128; s > 0; s >>= 1) {
        if (t < s) sh[t] += sh[t + s];
        __syncthreads();
    }
    if (t == 0) {
        atomicExch(&bsum[blockIdx.x], sh[0]);
        __threadfence();
        int dd = atomicAdd(done, 1);
        lastf = (dd == (int)gridDim.x - 1) ? 1 : 0;
    }
    __syncthreads();
    if (lastf) {
        int v = (t < nb) ? atomicAdd(&bsum[t], 0) : 0;
        sh[t] = v;
        __syncthreads();
        for (int dl = 1; dl < 256; dl <<= 1) {
            int u = (t >= dl) ? sh[t - dl] : 0;
            __syncthreads();
            sh[t] += u;
            __syncthreads();
        }
        if (t < nb) boff[t] = sh[t] - v;
        if (t == 255) rowptr[n] = sh[255];
    }
}

__global__ __launch_bounds__(256) void scan3_k(const int* __restrict__ degi,
        const int* __restrict__ boff, int* __restrict__ rowptr, int n) {
    __shared__ int sh[256];
    int t = threadIdx.x;
    int i = blockIdx.x * 256 + t;
    int v = (i < n) ? degi[i] : 0;
    sh[t] = v;
    __syncthreads();
    for (int d = 1; d < 256; d <<= 1) {
        int u = (t >= d) ? sh[t - d] : 0;
        __syncthreads();
        sh[t] += u;
        __syncthreads();
    }
    if (i < n) rowptr[i] = boff[blockIdx.x] + sh[t] - v;
}

__global__ __launch_bounds__(256) void csr_bucket_k(const int* __restrict__ ei,
        const int* __restrict__ rowptr, u32* __restrict__ gcnt, u32* __restrict__ ebuf) {
    __shared__ u32 bh[NBUCK];
    __shared__ u32 cursor[NBUCK];
    int t = threadIdx.x;
    for (int i = t; i < NBUCK; i += 256) bh[i] = 0;
    __syncthreads();
    int e0 = blockIdx.x * EPB;
    int2 ed[8]; int nb[8];
#pragma unroll
    for (int i = 0; i < 8; ++i) {
        int e = e0 + t + i * 256;
        if (e < N_EDGES) {
            ed[i] = ((const int2*)ei)[e];
            nb[i] = ed[i].y >> 7;
            atomicAdd(&bh[nb[i]], 1u);
        } else nb[i] = -1;
    }
    __syncthreads();
    for (int b = t; b < NBUCK; b += 256) {
        u32 c = bh[b];
        if (c) cursor[b] = (u32)rowptr[b << 7] + atomicAdd(&gcnt[b], c);
    }
    __syncthreads();
#pragma unroll
    for (int i = 0; i < 8; ++i) {
        if (nb[i] >= 0) {
            u32 pos = atomicAdd(&cursor[nb[i]], 1u);
            ebuf[pos] = ((u32)(ed[i].y & 127) << 16) | (u32)ed[i].x;
        }
    }
}

__global__ __launch_bounds__(256) void csr_build_k(const u32* __restrict__ ebuf,
        const int* __restrict__ rowptr, int* __restrict__ csr) {
    __shared__ int rp[129];
    __shared__ int fcnt[128];
    __shared__ int seg[SEG_CAP];
    int b = blockIdx.x;
    int lo = b << 7;
    int nn = min(128, N_NODES - lo);
    int t = threadIdx.x;
    if (t <= nn) rp[t] = rowptr[lo + t];
    if (t < 128) fcnt[t] = 0;
    __syncthreads();
    int segbase = rp[0];
    int segsz = rp[nn] - segbase;
    if (segsz <= SEG_CAP) {
        for (int idx = t; idx < segsz; idx += 256) {
            u32 v = ebuf[segbase + idx];
            int dl = v >> 16;
            int slot = rp[dl] - segbase + atomicAdd(&fcnt[dl], 1);
            seg[slot] = (int)(v & 0xFFFFu);
        }
        __syncthreads();
        for (int idx = t; idx < segsz; idx += 256) csr[segbase + idx] = seg[idx];
    } else {
        for (int idx = t; idx < segsz; idx += 256) {
            u32 v = ebuf[segbase + idx];
            int dl = v >> 16;
            int slot = rp[dl] + atomicAdd(&fcnt[dl], 1);
            csr[slot] = (int)(v & 0xFFFFu);
        }
    }
}

__global__ __launch_bounds__(256) void gather_k(const int* __restrict__ rowptr,
        const int* __restrict__ csr, const float* __restrict__ dinv,
        const ushort_t* __restrict__ hb, const float* __restrict__ bias,
        float* __restrict__ out, int n) {
    int node = blockIdx.x * 4 + (threadIdx.x >> 6);
    if (node >= n) return;
    int lane = threadIdx.x & 63;
    float di = dinv[node];
    float2 bv = *(const float2*)&bias[2*lane];
    ushort2 hs = *(const ushort2*)&hb[(size_t)node * HDIM + 2*lane];
    float s2 = di * di;
    float accx = s2 * h2f(hs.x) + bv.x;
    float accy = s2 * h2f(hs.y) + bv.y;
    int rs = rowptr[node], re = rowptr[node + 1];
    for (int base = rs; base < re; base += 64) {
        int cnt = min(64, re - base);
        int srcv = 0; float cv = 0.0f;
        if (lane < cnt) { srcv = csr[base + lane]; cv = di * dinv[srcv]; }
        int j = 0;
        for (; j + 8 <= cnt; j += 8) {
            int s0 = __shfl(srcv, j+0, 64); int s1 = __shfl(srcv, j+1, 64);
            int s2i= __shfl(srcv, j+2, 64); int s3 = __shfl(srcv, j+3, 64);
            int s4 = __shfl(srcv, j+4, 64); int s5 = __shfl(srcv, j+5, 64);
            int s6 = __shfl(srcv, j+6, 64); int s7 = __shfl(srcv, j+7, 64);
            float c0 = __shfl(cv, j+0, 64); float c1 = __shfl(cv, j+1, 64);
            float c2 = __shfl(cv, j+2, 64); float c3 = __shfl(cv, j+3, 64);
            float c4 = __shfl(cv, j+4, 64); float c5 = __shfl(cv, j+5, 64);
            float c6 = __shfl(cv, j+6, 64); float c7 = __shfl(cv, j+7, 64);
            ushort2 v0 = *(const ushort2*)&hb[(size_t)s0 * HDIM + 2*lane];
            ushort2 v1 = *(const ushort2*)&hb[(size_t)s1 * HDIM + 2*lane];
            ushort2 v2 = *(const ushort2*)&hb[(size_t)s2i* HDIM + 2*lane];
            ushort2 v3 = *(const ushort2*)&hb[(size_t)s3 * HDIM + 2*lane];
            ushort2 v4 = *(const ushort2*)&hb[(size_t)s4 * HDIM + 2*lane];
            ushort2 v5 = *(const ushort2*)&hb[(size_t)s5 * HDIM + 2*lane];
            ushort2 v6 = *(const ushort2*)&hb[(size_t)s6 * HDIM + 2*lane];
            ushort2 v7 = *(const ushort2*)&hb[(size_t)s7 * HDIM + 2*lane];
            accx += c0*h2f(v0.x); accy += c0*h2f(v0.y);
            accx += c1*h2f(v1.x); accy += c1*h2f(v1.y);
            accx += c2*h2f(v2.x); accy += c2*h2f(v2.y);
            accx += c3*h2f(v3.x); accy += c3*h2f(v3.y);
            accx += c4*h2f(v4.x); accy += c4*h2f(v4.y);
            accx += c5*h2f(v5.x); accy += c5*h2f(v5.y);
            accx += c6*h2f(v6.x); accy += c6*h2f(v6.y);
            accx += c7*h2f(v7.x); accy += c7*h2f(v7.y);
        }
        for (; j < cnt; ++j) {
            int src = __shfl(srcv, j, 64);
            float c  = __shfl(cv, j, 64);
            ushort2 sv = *(const ushort2*)&hb[(size_t)src * HDIM + 2*lane];
            accx += c * h2f(sv.x);
            accy += c * h2f(sv.y);
        }
    }
    float2 o; o.x = accx; o.y = accy;
    *(float2*)&out[(size_t)node * HDIM + 2*lane] = o;
}

__global__ __launch_bounds__(256) void gather_pool_k(const int* __restrict__ rowptr,
        const int* __restrict__ csr, const int* __restrict__ n2o,
        const int2* __restrict__ pinfo, const float* __restrict__ dinvp,
        const ushort_t* __restrict__ hb, const float* __restrict__ bias,
        float* __restrict__ out) {
    __shared__ int   sns[4][64];
    __shared__ float scf[4][64];
    int k = blockIdx.x * 4 + (threadIdx.x >> 6);
    if (k >= KSEL) return;
    int wid = threadIdx.x >> 6, lane = threadIdx.x & 63;
    float di = dinvp[k];
    float2 bv = *(const float2*)&bias[2*lane];
    ushort2 hs = *(const ushort2*)&hb[(size_t)k * HDIM + 2*lane];
    float s2 = di * di;
    float accx = s2 * h2f(hs.x) + bv.x;
    float accy = s2 * h2f(hs.y) + bv.y;
    int old = n2o[k];
    int rs = rowptr[old], re = rowptr[old + 1];
    for (int base = rs; base < re; base += 64) {
        int span = min(64, re - base);
        int ns = -1; float dv = 0.0f;
        if (lane < span) {
            int2 pi = pinfo[csr[base + lane]];
            ns = pi.x; dv = __int_as_float(pi.y);
        }
        bool sel = (ns >= 0);
        u64 m = __ballot(sel);
        int rank = __popcll(m & ((1ull << lane) - 1ull));
        if (sel) { sns[wid][rank] = ns; scf[wid][rank] = di * dv; }
        int cnt = __popcll(m);
        __threadfence_block();
        int j = 0;
        for (; j + 8 <= cnt; j += 8) {
            int s0 = sns[wid][j+0]; int s1 = sns[wid][j+1];
            int s2i= sns[wid][j+2]; int s3 = sns[wid][j+3];
            int s4 = sns[wid][j+4]; int s5 = sns[wid][j+5];
            int s6 = sns[wid][j+6]; int s7 = sns[wid][j+7];
            float c0 = scf[wid][j+0]; float c1 = scf[wid][j+1];
            float c2 = scf[wid][j+2]; float c3 = scf[wid][j+3];
            float c4 = scf[wid][j+4]; float c5 = scf[wid][j+5];
            float c6 = scf[wid][j+6]; float c7 = scf[wid][j+7];
            ushort2 v0 = *(const ushort2*)&hb[(size_t)s0 * HDIM + 2*lane];
            ushort2 v1 = *(const ushort2*)&hb[(size_t)s1 * HDIM + 2*lane];
            ushort2 v2 = *(const ushort2*)&hb[(size_t)s2i* HDIM + 2*lane];
            ushort2 v3 = *(const ushort2*)&hb[(size_t)s3 * HDIM + 2*lane];
            ushort2 v4 = *(const ushort2*)&hb[(size_t)s4 * HDIM + 2*lane];
            ushort2 v5 = *(const ushort2*)&hb[(size_t)s5 * HDIM + 2*lane];
            ushort2 v6 = *(const ushort2*)&hb[(size_t)s6 * HDIM + 2*lane];
            ushort2 v7 = *(const ushort2*)&hb[(size_t)s7 * HDIM + 2*lane];
            accx += c0*h2f(v0.x); accy += c0*h2f(v0.y);
            accx += c1*h2f(v1.x); accy += c1*h2f(v1.y);
            accx += c2*h2f(v2.x); accy += c2*h2f(v2.y);
            accx += c3*h2f(v3.x); accy += c3*h2f(v3.y);
            accx += c4*h2f(v4.x); accy += c4*h2f(v4.y);
            accx += c5*h2f(v5.x); accy += c5*h2f(v5.y);
            accx += c6*h2f(v6.x); accy += c6*h2f(v6.y);
            accx += c7*h2f(v7.x); accy += c7*h2f(v7.y);
        }
        for (; j < cnt; ++j) {
            int src = sns[wid][j];
            float c = scf[wid][j];
            ushort2 sv = *(const ushort2*)&hb[(size_t)src * HDIM + 2*lane];
            accx += c * h2f(sv.x);
            accy += c * h2f(sv.y);
        }
    }
    float2 o; o.x = accx; o.y = accy;
    *(float2*)&out[(size_t)k * HDIM + 2*lane] = o;
}

template<bool RELU_IN>
__global__ __launch_bounds__(256) void matmul_k(const float* __restrict__ in,
        const float* __restrict__ W, ushort_t* __restrict__ outb, int rows) {
    __shared__ _Float16 Wf[4][8][64][8];
    int t = threadIdx.x;
    int rbase = blockIdx.x * MMB_ROWS;
    for (int idx = t; idx < HDIM * HDIM; idx += 256) {
        int k = idx >> 7, j = idx & 127;
        int kk = k >> 5, kgrp = (k >> 3) & 3, i = k & 7;
        int ct = j >> 4, lrow = j & 15;
        Wf[kk][ct][kgrp * 16 + lrow][i] = (_Float16)W[idx];
    }
    int wid = t >> 6, lane = t & 63;
    int lrow = lane & 15, kgrp = lane >> 4;
    int arow = rbase + wid * 16 + lrow;
    bool rowok = (arow < rows);
    const float* arp = in + (size_t)(rowok ? arow : 0) * HDIM + kgrp * 8;
    half8 a[4];
#pragma unroll
    for (int kk = 0; kk < 4; ++kk) {
        float4 lo = rowok ? *(const float4*)(arp + kk * 32)     : float4{0,0,0,0};
        float4 hi = rowok ? *(const float4*)(arp + kk * 32 + 4) : float4{0,0,0,0};
        if (RELU_IN) {
            lo.x = fmaxf(lo.x, 0.f); lo.y = fmaxf(lo.y, 0.f);
            lo.z = fmaxf(lo.z, 0.f); lo.w = fmaxf(lo.w, 0.f);
            hi.x = fmaxf(hi.x, 0.f); hi.y = fmaxf(hi.y, 0.f);
            hi.z = fmaxf(hi.z, 0.f); hi.w = fmaxf(hi.w, 0.f);
        }
        a[kk][0] = (_Float16)lo.x; a[kk][1] = (_Float16)lo.y;
        a[kk][2] = (_Float16)lo.z; a[kk][3] = (_Float16)lo.w;
        a[kk][4] = (_Float16)hi.x; a[kk][5] = (_Float16)hi.y;
        a[kk][6] = (_Float16)hi.z; a[kk][7] = (_Float16)hi.w;
    }
    __syncthreads();
    floatx4 zero4 = {0.0f, 0.0f, 0.0f, 0.0f};
    floatx4 acc[8];
#pragma unroll
    for (int ct = 0; ct < 8; ++ct) acc[ct] = zero4;
#pragma unroll
    for (int kk = 0; kk < 4; ++kk) {
#pragma unroll
        for (int ct = 0; ct < 8; ++ct) {
            half8 b = *(const half8*)&Wf[kk][ct][lane][0];
            acc[ct] = __builtin_amdgcn_mfma_f32_16x16x32_f16(a[kk], b, acc[ct], 0, 0, 0);
        }
    }
    int orow0 = rbase + wid * 16 + kgrp * 4;
#pragma unroll
    for (int ct = 0; ct < 8; ++ct) {
#pragma unroll
        for (int i = 0; i < 4; ++i) {
            int row = orow0 + i;
            if (row < rows) {
                _Float16 hv = (_Float16)acc[ct][i];
                outb[(size_t)row * HDIM + ct * 16 + lrow] = *(ushort_t*)&hv;
            }
        }
    }
}

// Fused top-K pipeline: score+key -> 4x12bit radix select -> select -> hp+pool_deg.
// TK_BLOCKS persistent blocks with device-scope barriers (arrive ctr + ready flag).
__global__ __launch_bounds__(256) void topk_fused_k(const float* __restrict__ h,
        const float* __restrict__ pn, float* __restrict__ score, u64* __restrict__ key,
        SelState* st, u32* __restrict__ ghist, int* __restrict__ sync,
        int2* __restrict__ pinfo, int* __restrict__ n2o,
        const int* __restrict__ rowptr, const int* __restrict__ csr,
        float* __restrict__ dinvp, float* __restrict__ hp) {
    __shared__ u32 lh[4096];
    __shared__ u32 sct[256];
    __shared__ u64 spref;
    __shared__ int skrem;
    __shared__ int lastf;
    int t = threadIdx.x;
    int lane = t & 63;
    int gw = blockIdx.x * 4 + (t >> 6);

    // phase 1: scores + keys
    float pnl = pn[lane], pnh = pn[lane + 64];
    for (int node = gw; node < N_NODES; node += TK_BLOCKS * 4) {
        const float* row = h + (size_t)node * HDIM;
        float sv = fmaxf(row[lane], 0.f) * pnl + fmaxf(row[lane+64], 0.f) * pnh;
#pragma unroll
        for (int o = 32; o > 0; o >>= 1) sv += __shfl_xor(sv, o, 64);
        if (lane == 0) {
            score[node] = sv;
            u32 u = __float_as_uint(sv);
            u = (u & 0x80000000u) ? ~u : (u | 0x80000000u);
            key[node] = ((u64)u << 16) | (u64)(65535 - node);
        }
    }
    // barrier (phase1 -> radix)
    __syncthreads();
    if (t == 0) {
        __threadfence();
        int v = atomicAdd(&sync[10], 1);
        if (v == TK_BLOCKS - 1) atomicExch(&sync[11], 1);
        else while (atomicAdd(&sync[11], 0) == 0) __builtin_amdgcn_s_sleep(8);
    }
    __syncthreads();
    __threadfence();

    // 4 radix passes, 12-bit digits
    for (int pass = 0; pass < 4; ++pass) {
        int dsh = 36 - 12 * pass;
        if (t == 0) spref = atomicAdd((unsigned long long*)&st->prefix, 0ull);
        __syncthreads();
        u64 pref = spref;
        for (int b = t; b < 4096; b += 256) lh[b] = 0;
        __syncthreads();
        for (int i = blockIdx.x * 256 + t; i < N_NODES; i += TK_BLOCKS * 256) {
            u64 k = key[i];
            if (((k ^ pref) >> (dsh + 12)) == 0)
                atomicAdd(&lh[(int)((k >> dsh) & 4095)], 1u);
        }
        __syncthreads();
        for (int b = t; b < 4096; b += 256) {
            u32 v = lh[b];
            if (v) atomicAdd(&ghist[pass * 4096 + b], v);
        }
        __threadfence();
        if (t == 0) {
            int v = atomicAdd(&sync[2 + pass], 1);
            lastf = (v == TK_BLOCKS - 1) ? 1 : 0;
        }
        __syncthreads();
        if (lastf) {
            for (int b = t; b < 4096; b += 256) lh[b] = atomicAdd(&ghist[pass * 4096 + b], 0u);
            if (t == 0) skrem = atomicAdd(&st->krem, 0);
            __syncthreads();
            int krem = skrem;
            u32 ctt = 0;
#pragma unroll
            for (int j = 0; j < 16; ++j) ctt += lh[t * 16 + j];
            sct[t] = ctt;
            __syncthreads();
            for (int d = 1; d < 256; d <<= 1) {
                u32 add = (t + d < 256) ? sct[t + d] : 0u;
                __syncthreads();
                sct[t] += add;
                __syncthreads();
            }
            u32 incl = sct[t];
            u32 excl = incl - ctt;
            if ((int)excl < krem && (int)incl >= krem) {
                u32 run = excl;
                int bsel = 0; u32 csel = 0;
                for (int j = 15; j >= 0; --j) {
                    u32 c = lh[t * 16 + j];
                    run += c;
                    if ((int)run >= krem) { bsel = t * 16 + j; csel = c; break; }
                }
                int newk = krem - (int)(run - csel);
                atomicExch((unsigned long long*)&st->prefix, spref | ((u64)bsel << dsh));
                atomicExch(&st->krem, newk);
            }
            __syncthreads();
            __threadfence();
            if (t == 0) atomicExch(&sync[6 + pass], 1);
        } else {
            if (t == 0) while (atomicAdd(&sync[6 + pass], 0) == 0) __builtin_amdgcn_s_sleep(8);
        }
        __syncthreads();
        __threadfence();
    }

    // select phase
    if (t == 0) spref = atomicAdd((unsigned long long*)&st->prefix, 0ull);
    __syncthreads();
    u64 pref = spref;
    for (int i = blockIdx.x * 256 + t; i < N_NODES; i += TK_BLOCKS * 256) {
        if (key[i] >= pref) {
            int pos = atomicAdd(&st->cnt, 1);
            pinfo[i].x = pos;
            n2o[pos] = i;
        } else {
            pinfo[i].x = -1;
        }
    }
    // barrier (select -> hp/pool_deg)
    __syncthreads();
    if (t == 0) {
        __threadfence();
        int v = atomicAdd(&sync[12], 1);
        if (v == TK_BLOCKS - 1) atomicExch(&sync[13], 1);
        else while (atomicAdd(&sync[13], 0) == 0) __builtin_amdgcn_s_sleep(8);
    }
    __syncthreads();
    __threadfence();

    // phase 4: hp + pooled degree + dinvp + pinfo.dv
    for (int k = gw; k < KSEL; k += TK_BLOCKS * 4) {
        int old = n2o[k];
        float tv = tanhf(score[old]);
        const float* row = h + (size_t)old * HDIM;
        hp[(size_t)k * HDIM + lane]      = fmaxf(row[lane], 0.f) * tv;
        hp[(size_t)k * HDIM + lane + 64] = fmaxf(row[lane+64], 0.f) * tv;
        int rs = rowptr[old], re = rowptr[old + 1];
        int cnt = 0;
        for (int base = rs; base < re; base += 64) {
            int span = min(64, re - base);
            bool sel = false;
            if (lane < span) sel = (pinfo[csr[base + lane]].x >= 0);
            cnt += __popcll(__ballot(sel));
        }
        if (lane == 0) {
            float dv = rsqrtf((float)cnt + 1.0f);
            dinvp[k] = dv;
            pinfo[old].y = __float_as_int(dv);
        }
    }
}

__global__ __launch_bounds__(256) void pool_stage1_k(const float* __restrict__ h,
        const int* __restrict__ n2o, const int* __restrict__ batch,
        float* __restrict__ partial, int* __restrict__ pcnt) {
    __shared__ float ls[NBATCH * HDIM];
    __shared__ int   lc[NBATCH];
    int t = threadIdx.x;
    for (int i = t; i < NBATCH * HDIM; i += 256) ls[i] = 0.0f;
    if (t < NBATCH) lc[t] = 0;
    __syncthreads();
    int wid = t >> 6, lane = t & 63;
    int start = blockIdx.x * POOL_CHUNK;
    int end = min(start + POOL_CHUNK, KSEL);
    for (int k = start + wid; k < end; k += 4) {
        int b = batch[n2o[k]];
        float2 hv = *(const float2*)&h[(size_t)k * HDIM + 2*lane];
        atomicAdd(&ls[b * HDIM + 2*lane],     fmaxf(hv.x, 0.0f));
        atomicAdd(&ls[b * HDIM + 2*lane + 1], fmaxf(hv.y, 0.0f));
        if (lane == 0) atomicAdd(&lc[b], 1);
    }
    __syncthreads();
    float* pb = partial + (size_t)blockIdx.x * (NBATCH * HDIM);
    for (int i = t; i < NBATCH * HDIM; i += 256) pb[i] = ls[i];
    if (t < NBATCH) pcnt[blockIdx.x * NBATCH + t] = lc[t];
}

__global__ __launch_bounds__(256) void pool_stage2_k(const float* __restrict__ partial,
        const int* __restrict__ pcnt, float* __restrict__ sums, float* __restrict__ cntb) {
    int i = blockIdx.x * 256 + threadIdx.x;
    if (i >= NBATCH * HDIM) return;
    float s = 0.0f;
    for (int p = 0; p < POOL_BLOCKS; ++p) s += partial[(size_t)p * NBATCH * HDIM + i];
    sums[i] = s;
    if (i < NBATCH) {
        int c = 0;
        for (int p = 0; p < POOL_BLOCKS; ++p) c += pcnt[p * NBATCH + i];
        cntb[i] = (float)c;
    }
}

// fc1 (grid) + fc2/log_softmax (last block)
__global__ __launch_bounds__(256) void fc_k(const float* __restrict__ sums,
        const float* __restrict__ cntb, const float* __restrict__ W1b,
        const float* __restrict__ b1b, const float* __restrict__ W2b,
        const float* __restrict__ b2b, float* __restrict__ gbuf,
        float* __restrict__ out, int* done) {
    int t = threadIdx.x;
    int gid = blockIdx.x * 256 + t;
    if (gid < NBATCH * HDIM) {
        int b = gid >> 7, j = gid & 127;
        float inv = 1.0f / fmaxf(cntb[b], 1.0f);
        float acc = 0.0f;
        for (int k = 0; k < HDIM; ++k) acc += sums[b * HDIM + k] * W1b[k * HDIM + j];
        gbuf[gid] = fmaxf(acc * inv + b1b[j], 0.0f);
    }
    __threadfence();
    __shared__ int lastf;
    if (t == 0) lastf = (atomicAdd(done, 1) == (int)gridDim.x - 1) ? 1 : 0;
    __syncthreads();
    if (!lastf || t >= NBATCH) return;
    __threadfence();
    int b = t;
    float l[NCLS];
    for (int c = 0; c < NCLS; ++c) {
        float acc = b2b[c];
        for (int k = 0; k < HDIM; ++k) acc += gbuf[b * HDIM + k] * W2b[k * NCLS + c];
        l[c] = acc;
    }
    float m = fmaxf(l[0], fmaxf(l[1], l[2]));
    float sum = expf(l[0]-m) + expf(l[1]-m) + expf(l[2]-m);
    float ls = logf(sum);
    for (int c = 0; c < NCLS; ++c) out[b * NCLS + c] = l[c] - m - ls;
}

extern "C" void kernel_launch(void* const* d_in, const int* in_sizes, int n_in,
                              void* d_out, int out_size, void* d_ws, size_t ws_size,
                              hipStream_t stream) {
    const float* x    = (const float*)d_in[0];
    const int*   ei   = (const int*)d_in[1];
    const int*   batch= (const int*)d_in[2];
    const float* W1   = (const float*)d_in[3];
    const float* b1   = (const float*)d_in[4];
    const float* W2   = (const float*)d_in[5];
    const float* b2   = (const float*)d_in[6];
    const float* p    = (const float*)d_in[7];
    const float* W3   = (const float*)d_in[8];
    const float* b3   = (const float*)d_in[9];
    const float* W4   = (const float*)d_in[10];
    const float* b4   = (const float*)d_in[11];
    const float* fcW1 = (const float*)d_in[12];
    const float* fcb1 = (const float*)d_in[13];
    const float* fcW2 = (const float*)d_in[14];
    const float* fcb2 = (const float*)d_in[15];
    float* out = (float*)d_out;

    char* ws = (char*)d_ws;
    size_t off = 0;
    auto alloc = [&](size_t bytes) {
        size_t r = off;
        off = (off + bytes + 255) & ~(size_t)255;
        return r;
    };
    float* A     = (float*)(ws + alloc((size_t)N_NODES * HDIM * 4));
    float* Bf    = (float*)(ws + alloc((size_t)N_NODES * HDIM * 4));
    ushort_t* Hbf= (ushort_t*)(ws + alloc((size_t)N_NODES * HDIM * 2));
    u64*   key   = (u64*)  (ws + alloc((size_t)N_NODES * 8));
    float* score = (float*)(ws + alloc((size_t)N_NODES * 4));
    int2*  pinfo = (int2*) (ws + alloc((size_t)N_NODES * 8));
    int*   n2o   = (int*)  (ws + alloc((size_t)KSEL * 4));
    float* pn    = (float*)(ws + alloc(HDIM * 4));
    float* gbuf  = (float*)(ws + alloc(NBATCH * HDIM * 4));
    SelState* st = (SelState*)(ws + alloc(256));
    float* dinv1 = (float*)(ws + alloc((size_t)N_NODES * 4));
    float* dinvp = (float*)(ws + alloc((size_t)KSEL * 4));
    int*   rowptr= (int*)  (ws + alloc((size_t)(N_NODES + 1) * 4));
    int*   csr   = (int*)  (ws + alloc((size_t)N_EDGES * 4));
    u32*   ebuf  = (u32*)  (ws + alloc((size_t)N_EDGES * 4));
    int*   bsum  = (int*)  (ws + alloc(256 * 4));
    int*   boff  = (int*)  (ws + alloc(256 * 4));
    float* partial=(float*)(ws + alloc((size_t)POOL_BLOCKS * NBATCH * HDIM * 4));
    int*   pcnt  = (int*)  (ws + alloc((size_t)POOL_BLOCKS * NBATCH * 4));
    float* sums  = (float*)(ws + alloc(NBATCH * HDIM * 4));
    float* cntb  = (float*)(ws + alloc(NBATCH * 4));
    // zeroed region: degi, gcnt, ghist, sync
    size_t z1 = off;
    int*   degi  = (int*)(ws + alloc((size_t)N_NODES * 4));
    u32*   gcnt  = (u32*)(ws + alloc((size_t)NBUCK * 4));
    u32*   ghist = (u32*)(ws + alloc(4 * 4096 * 4));
    int*   sync  = (int*)(ws + alloc(32 * 4));
    size_t z1e = off;

    hipMemsetAsync(ws + z1, 0, z1e - z1, stream);
    init_pnorm_k<<<1, HDIM, 0, stream>>>(p, pn, st);

    const int eg   = (N_EDGES + 255) / 256;
    const int ng   = (N_NODES + 255) / 256;
    const int mm_grid_n = (N_NODES + MMB_ROWS - 1) / MMB_ROWS;
    const int mm_grid_k = (KSEL + MMB_ROWS - 1) / MMB_ROWS;
    const int gt_grid_n = (N_NODES + 3) / 4;
    const int gt_grid_k = (KSEL + 3) / 4;

    // full-graph CSR (bucketed build)
    deg_full_k<<<eg, 256, 0, stream>>>(ei, degi);
    scan12_k<<<ng, 256, 0, stream>>>(degi, bsum, boff, dinv1, rowptr, N_NODES, ng, sync + 0);
    scan3_k<<<ng, 256, 0, stream>>>(degi, boff, rowptr, N_NODES);
    csr_bucket_k<<<S1_BLOCKS, 256, 0, stream>>>(ei, rowptr, gcnt, ebuf);
    csr_build_k<<<NBUCK, 256, 0, stream>>>(ebuf, rowptr, csr);

    // conv1 + conv2
    matmul_k<false><<<mm_grid_n, 256, 0, stream>>>(x, W1, Hbf, N_NODES);
    gather_k<<<gt_grid_n, 256, 0, stream>>>(rowptr, csr, dinv1, Hbf, b1, Bf, N_NODES);
    matmul_k<true><<<mm_grid_n, 256, 0, stream>>>(Bf, W2, Hbf, N_NODES);
    gather_k<<<gt_grid_n, 256, 0, stream>>>(rowptr, csr, dinv1, Hbf, b2, Bf, N_NODES);

    // fused top-K pipeline (score -> radix -> select -> hp + pool_deg)
    topk_fused_k<<<TK_BLOCKS, 256, 0, stream>>>(Bf, pn, score, key, st, ghist, sync,
                                                pinfo, n2o, rowptr, csr, dinvp, A);

    // conv3 + conv4 (pooled, filtered gather over full CSR)
    matmul_k<false><<<mm_grid_k, 256, 0, stream>>>(A, W3, Hbf, KSEL);
    gather_pool_k<<<gt_grid_k, 256, 0, stream>>>(rowptr, csr, n2o, pinfo, dinvp, Hbf, b3, Bf);
    matmul_k<true><<<mm_grid_k, 256, 0, stream>>>(Bf, W4, Hbf, KSEL);
    gather_pool_k<<<gt_grid_k, 256, 0, stream>>>(rowptr, csr, n2o, pinfo, dinvp, Hbf, b4, A);

    // batch mean pool + FC head (fc2 fused as last-block)
    pool_stage1_k<<<POOL_BLOCKS, 256, 0, stream>>>(A, n2o, batch, partial, pcnt);
    pool_stage2_k<<<(NBATCH * HDIM + 255) / 256, 256, 0, stream>>>(partial, pcnt, sums, cntb);
    fc_k<<<(NBATCH * HDIM + 255) / 256, 256, 0, stream>>>(sums, cntb, fcW1, fcb1,
                                                          fcW2, fcb2, gbuf, out, sync + 14);
}

// Round 17
// 677.613 us; speedup vs baseline: 1.1233x; 1.1233x over previous
//
#include <hip/hip_runtime.h>

#define N_NODES 50000
#define N_EDGES 800000
#define HDIM    128
#define NBATCH  64
#define NCLS    3
#define KSEL    (N_NODES/2)
#define MMB_ROWS 64
#define TK_BLOCKS 512
#define POOL_BLOCKS 256
#define POOL_CHUNK  ((KSEL + POOL_BLOCKS - 1) / POOL_BLOCKS)
#define NBUCK ((N_NODES + 127) >> 7)
#define EPB   2048
#define S1_BLOCKS ((N_EDGES + EPB - 1) / EPB)
#define SEG_CAP 4096
#define SYNC_SLOT 64   // ints per sync slot (256B): counter at +0, flag at +32

typedef unsigned long long u64;
typedef unsigned int u32;
typedef unsigned short ushort_t;
typedef _Float16 half8 __attribute__((ext_vector_type(8)));
typedef float floatx4 __attribute__((ext_vector_type(4)));

struct SelState { u64 prefix; int krem; int cnt; };

__device__ __forceinline__ float h2f(ushort_t u) {
    _Float16 h = *(_Float16*)&u;
    return (float)h;
}
__device__ __forceinline__ int agent_load(const int* p) {
    return __hip_atomic_load(p, __ATOMIC_RELAXED, __HIP_MEMORY_SCOPE_AGENT);
}
__device__ __forceinline__ u32 agent_load_u32(const u32* p) {
    return __hip_atomic_load(p, __ATOMIC_RELAXED, __HIP_MEMORY_SCOPE_AGENT);
}

__global__ void init_pnorm_k(const float* __restrict__ p, float* __restrict__ pn,
        SelState* st) {
    __shared__ float red[HDIM];
    int t = threadIdx.x;
    float v = p[t];
    red[t] = v * v;
    __syncthreads();
    for (int s = HDIM/2; s > 0; s >>= 1) {
        if (t < s) red[t] += red[t+s];
        __syncthreads();
    }
    pn[t] = v / sqrtf(red[0]);
    if (t == 0) { st->prefix = 0ull; st->krem = KSEL; st->cnt = 0; }
}

__global__ void deg_full_k(const int* __restrict__ ei, int* __restrict__ degi) {
    int e = blockIdx.x * blockDim.x + threadIdx.x;
    if (e >= N_EDGES) return;
    int2 ed = ((const int2*)ei)[e];
    atomicAdd(&degi[ed.y], 1);
}

__global__ __launch_bounds__(256) void scan12_k(const int* __restrict__ degi,
        int* __restrict__ bsum, int* __restrict__ boff, float* __restrict__ dinv,
        int* __restrict__ rowptr, int n, int nb, int* done) {
    __shared__ int sh[256];
    __shared__ int lastf;
    int t = threadIdx.x;
    int i = blockIdx.x * 256 + t;
    int d = (i < n) ? degi[i] : 0;
    if (i < n) dinv[i] = rsqrtf((float)d + 1.0f);
    sh[t] = d;
    __syncthreads();
    for (int s = 128; s > 0; s >>= 1) {
        if (t < s) sh[t] += sh[t + s];
        __syncthreads();
    }
    if (t == 0) {
        atomicExch(&bsum[blockIdx.x], sh[0]);
        __threadfence();
        int dd = atomicAdd(done, 1);
        lastf = (dd == (int)gridDim.x - 1) ? 1 : 0;
    }
    __syncthreads();
    if (lastf) {
        int v = (t < nb) ? atomicAdd(&bsum[t], 0) : 0;
        sh[t] = v;
        __syncthreads();
        for (int dl = 1; dl < 256; dl <<= 1) {
            int u = (t >= dl) ? sh[t - dl] : 0;
            __syncthreads();
            sh[t] += u;
            __syncthreads();
        }
        if (t < nb) boff[t] = sh[t] - v;
        if (t == 255) rowptr[n] = sh[255];
    }
}

__global__ __launch_bounds__(256) void scan3_k(const int* __restrict__ degi,
        const int* __restrict__ boff, int* __restrict__ rowptr, int n) {
    __shared__ int sh[256];
    int t = threadIdx.x;
    int i = blockIdx.x * 256 + t;
    int v = (i < n) ? degi[i] : 0;
    sh[t] = v;
    __syncthreads();
    for (int d = 1; d < 256; d <<= 1) {
        int u = (t >= d) ? sh[t - d] : 0;
        __syncthreads();
        sh[t] += u;
        __syncthreads();
    }
    if (i < n) rowptr[i] = boff[blockIdx.x] + sh[t] - v;
}

__global__ __launch_bounds__(256) void csr_bucket_k(const int* __restrict__ ei,
        const int* __restrict__ rowptr, u32* __restrict__ gcnt, u32* __restrict__ ebuf) {
    __shared__ u32 bh[NBUCK];
    __shared__ u32 cursor[NBUCK];
    int t = threadIdx.x;
    for (int i = t; i < NBUCK; i += 256) bh[i] = 0;
    __syncthreads();
    int e0 = blockIdx.x * EPB;
    int2 ed[8]; int nb[8];
#pragma unroll
    for (int i = 0; i < 8; ++i) {
        int e = e0 + t + i * 256;
        if (e < N_EDGES) {
            ed[i] = ((const int2*)ei)[e];
            nb[i] = ed[i].y >> 7;
            atomicAdd(&bh[nb[i]], 1u);
        } else nb[i] = -1;
    }
    __syncthreads();
    for (int b = t; b < NBUCK; b += 256) {
        u32 c = bh[b];
        if (c) cursor[b] = (u32)rowptr[b << 7] + atomicAdd(&gcnt[b], c);
    }
    __syncthreads();
#pragma unroll
    for (int i = 0; i < 8; ++i) {
        if (nb[i] >= 0) {
            u32 pos = atomicAdd(&cursor[nb[i]], 1u);
            ebuf[pos] = ((u32)(ed[i].y & 127) << 16) | (u32)ed[i].x;
        }
    }
}

__global__ __launch_bounds__(256) void csr_build_k(const u32* __restrict__ ebuf,
        const int* __restrict__ rowptr, int* __restrict__ csr) {
    __shared__ int rp[129];
    __shared__ int fcnt[128];
    __shared__ int seg[SEG_CAP];
    int b = blockIdx.x;
    int lo = b << 7;
    int nn = min(128, N_NODES - lo);
    int t = threadIdx.x;
    if (t <= nn) rp[t] = rowptr[lo + t];
    if (t < 128) fcnt[t] = 0;
    __syncthreads();
    int segbase = rp[0];
    int segsz = rp[nn] - segbase;
    if (segsz <= SEG_CAP) {
        for (int idx = t; idx < segsz; idx += 256) {
            u32 v = ebuf[segbase + idx];
            int dl = v >> 16;
            int slot = rp[dl] - segbase + atomicAdd(&fcnt[dl], 1);
            seg[slot] = (int)(v & 0xFFFFu);
        }
        __syncthreads();
        for (int idx = t; idx < segsz; idx += 256) csr[segbase + idx] = seg[idx];
    } else {
        for (int idx = t; idx < segsz; idx += 256) {
            u32 v = ebuf[segbase + idx];
            int dl = v >> 16;
            int slot = rp[dl] + atomicAdd(&fcnt[dl], 1);
            csr[slot] = (int)(v & 0xFFFFu);
        }
    }
}

__global__ __launch_bounds__(256) void gather_k(const int* __restrict__ rowptr,
        const int* __restrict__ csr, const float* __restrict__ dinv,
        const ushort_t* __restrict__ hb, const float* __restrict__ bias,
        float* __restrict__ out, int n) {
    int node = blockIdx.x * 4 + (threadIdx.x >> 6);
    if (node >= n) return;
    int lane = threadIdx.x & 63;
    float di = dinv[node];
    float2 bv = *(const float2*)&bias[2*lane];
    ushort2 hs = *(const ushort2*)&hb[(size_t)node * HDIM + 2*lane];
    float s2 = di * di;
    float accx = s2 * h2f(hs.x) + bv.x;
    float accy = s2 * h2f(hs.y) + bv.y;
    int rs = rowptr[node], re = rowptr[node + 1];
    for (int base = rs; base < re; base += 64) {
        int cnt = min(64, re - base);
        int srcv = 0; float cv = 0.0f;
        if (lane < cnt) { srcv = csr[base + lane]; cv = di * dinv[srcv]; }
        int j = 0;
        for (; j + 8 <= cnt; j += 8) {
            int s0 = __shfl(srcv, j+0, 64); int s1 = __shfl(srcv, j+1, 64);
            int s2i= __shfl(srcv, j+2, 64); int s3 = __shfl(srcv, j+3, 64);
            int s4 = __shfl(srcv, j+4, 64); int s5 = __shfl(srcv, j+5, 64);
            int s6 = __shfl(srcv, j+6, 64); int s7 = __shfl(srcv, j+7, 64);
            float c0 = __shfl(cv, j+0, 64); float c1 = __shfl(cv, j+1, 64);
            float c2 = __shfl(cv, j+2, 64); float c3 = __shfl(cv, j+3, 64);
            float c4 = __shfl(cv, j+4, 64); float c5 = __shfl(cv, j+5, 64);
            float c6 = __shfl(cv, j+6, 64); float c7 = __shfl(cv, j+7, 64);
            ushort2 v0 = *(const ushort2*)&hb[(size_t)s0 * HDIM + 2*lane];
            ushort2 v1 = *(const ushort2*)&hb[(size_t)s1 * HDIM + 2*lane];
            ushort2 v2 = *(const ushort2*)&hb[(size_t)s2i* HDIM + 2*lane];
            ushort2 v3 = *(const ushort2*)&hb[(size_t)s3 * HDIM + 2*lane];
            ushort2 v4 = *(const ushort2*)&hb[(size_t)s4 * HDIM + 2*lane];
            ushort2 v5 = *(const ushort2*)&hb[(size_t)s5 * HDIM + 2*lane];
            ushort2 v6 = *(const ushort2*)&hb[(size_t)s6 * HDIM + 2*lane];
            ushort2 v7 = *(const ushort2*)&hb[(size_t)s7 * HDIM + 2*lane];
            accx += c0*h2f(v0.x); accy += c0*h2f(v0.y);
            accx += c1*h2f(v1.x); accy += c1*h2f(v1.y);
            accx += c2*h2f(v2.x); accy += c2*h2f(v2.y);
            accx += c3*h2f(v3.x); accy += c3*h2f(v3.y);
            accx += c4*h2f(v4.x); accy += c4*h2f(v4.y);
            accx += c5*h2f(v5.x); accy += c5*h2f(v5.y);
            accx += c6*h2f(v6.x); accy += c6*h2f(v6.y);
            accx += c7*h2f(v7.x); accy += c7*h2f(v7.y);
        }
        for (; j < cnt; ++j) {
            int src = __shfl(srcv, j, 64);
            float c  = __shfl(cv, j, 64);
            ushort2 sv = *(const ushort2*)&hb[(size_t)src * HDIM + 2*lane];
            accx += c * h2f(sv.x);
            accy += c * h2f(sv.y);
        }
    }
    float2 o; o.x = accx; o.y = accy;
    *(float2*)&out[(size_t)node * HDIM + 2*lane] = o;
}

__global__ __launch_bounds__(256) void gather_pool_k(const int* __restrict__ rowptr,
        const int* __restrict__ csr, const int* __restrict__ n2o,
        const int2* __restrict__ pinfo, const float* __restrict__ dinvp,
        const ushort_t* __restrict__ hb, const float* __restrict__ bias,
        float* __restrict__ out) {
    __shared__ int   sns[4][64];
    __shared__ float scf[4][64];
    int k = blockIdx.x * 4 + (threadIdx.x >> 6);
    if (k >= KSEL) return;
    int wid = threadIdx.x >> 6, lane = threadIdx.x & 63;
    float di = dinvp[k];
    float2 bv = *(const float2*)&bias[2*lane];
    ushort2 hs = *(const ushort2*)&hb[(size_t)k * HDIM + 2*lane];
    float s2 = di * di;
    float accx = s2 * h2f(hs.x) + bv.x;
    float accy = s2 * h2f(hs.y) + bv.y;
    int old = n2o[k];
    int rs = rowptr[old], re = rowptr[old + 1];
    for (int base = rs; base < re; base += 64) {
        int span = min(64, re - base);
        int ns = -1; float dv = 0.0f;
        if (lane < span) {
            int2 pi = pinfo[csr[base + lane]];
            ns = pi.x; dv = __int_as_float(pi.y);
        }
        bool sel = (ns >= 0);
        u64 m = __ballot(sel);
        int rank = __popcll(m & ((1ull << lane) - 1ull));
        if (sel) { sns[wid][rank] = ns; scf[wid][rank] = di * dv; }
        int cnt = __popcll(m);
        __threadfence_block();
        int j = 0;
        for (; j + 8 <= cnt; j += 8) {
            int s0 = sns[wid][j+0]; int s1 = sns[wid][j+1];
            int s2i= sns[wid][j+2]; int s3 = sns[wid][j+3];
            int s4 = sns[wid][j+4]; int s5 = sns[wid][j+5];
            int s6 = sns[wid][j+6]; int s7 = sns[wid][j+7];
            float c0 = scf[wid][j+0]; float c1 = scf[wid][j+1];
            float c2 = scf[wid][j+2]; float c3 = scf[wid][j+3];
            float c4 = scf[wid][j+4]; float c5 = scf[wid][j+5];
            float c6 = scf[wid][j+6]; float c7 = scf[wid][j+7];
            ushort2 v0 = *(const ushort2*)&hb[(size_t)s0 * HDIM + 2*lane];
            ushort2 v1 = *(const ushort2*)&hb[(size_t)s1 * HDIM + 2*lane];
            ushort2 v2 = *(const ushort2*)&hb[(size_t)s2i* HDIM + 2*lane];
            ushort2 v3 = *(const ushort2*)&hb[(size_t)s3 * HDIM + 2*lane];
            ushort2 v4 = *(const ushort2*)&hb[(size_t)s4 * HDIM + 2*lane];
            ushort2 v5 = *(const ushort2*)&hb[(size_t)s5 * HDIM + 2*lane];
            ushort2 v6 = *(const ushort2*)&hb[(size_t)s6 * HDIM + 2*lane];
            ushort2 v7 = *(const ushort2*)&hb[(size_t)s7 * HDIM + 2*lane];
            accx += c0*h2f(v0.x); accy += c0*h2f(v0.y);
            accx += c1*h2f(v1.x); accy += c1*h2f(v1.y);
            accx += c2*h2f(v2.x); accy += c2*h2f(v2.y);
            accx += c3*h2f(v3.x); accy += c3*h2f(v3.y);
            accx += c4*h2f(v4.x); accy += c4*h2f(v4.y);
            accx += c5*h2f(v5.x); accy += c5*h2f(v5.y);
            accx += c6*h2f(v6.x); accy += c6*h2f(v6.y);
            accx += c7*h2f(v7.x); accy += c7*h2f(v7.y);
        }
        for (; j < cnt; ++j) {
            int src = sns[wid][j];
            float c = scf[wid][j];
            ushort2 sv = *(const ushort2*)&hb[(size_t)src * HDIM + 2*lane];
            accx += c * h2f(sv.x);
            accy += c * h2f(sv.y);
        }
    }
    float2 o; o.x = accx; o.y = accy;
    *(float2*)&out[(size_t)k * HDIM + 2*lane] = o;
}

template<bool RELU_IN>
__global__ __launch_bounds__(256) void matmul_k(const float* __restrict__ in,
        const float* __restrict__ W, ushort_t* __restrict__ outb, int rows) {
    __shared__ _Float16 Wf[4][8][64][8];
    int t = threadIdx.x;
    int rbase = blockIdx.x * MMB_ROWS;
    for (int idx = t; idx < HDIM * HDIM; idx += 256) {
        int k = idx >> 7, j = idx & 127;
        int kk = k >> 5, kgrp = (k >> 3) & 3, i = k & 7;
        int ct = j >> 4, lrow = j & 15;
        Wf[kk][ct][kgrp * 16 + lrow][i] = (_Float16)W[idx];
    }
    int wid = t >> 6, lane = t & 63;
    int lrow = lane & 15, kgrp = lane >> 4;
    int arow = rbase + wid * 16 + lrow;
    bool rowok = (arow < rows);
    const float* arp = in + (size_t)(rowok ? arow : 0) * HDIM + kgrp * 8;
    half8 a[4];
#pragma unroll
    for (int kk = 0; kk < 4; ++kk) {
        float4 lo = rowok ? *(const float4*)(arp + kk * 32)     : float4{0,0,0,0};
        float4 hi = rowok ? *(const float4*)(arp + kk * 32 + 4) : float4{0,0,0,0};
        if (RELU_IN) {
            lo.x = fmaxf(lo.x, 0.f); lo.y = fmaxf(lo.y, 0.f);
            lo.z = fmaxf(lo.z, 0.f); lo.w = fmaxf(lo.w, 0.f);
            hi.x = fmaxf(hi.x, 0.f); hi.y = fmaxf(hi.y, 0.f);
            hi.z = fmaxf(hi.z, 0.f); hi.w = fmaxf(hi.w, 0.f);
        }
        a[kk][0] = (_Float16)lo.x; a[kk][1] = (_Float16)lo.y;
        a[kk][2] = (_Float16)lo.z; a[kk][3] = (_Float16)lo.w;
        a[kk][4] = (_Float16)hi.x; a[kk][5] = (_Float16)hi.y;
        a[kk][6] = (_Float16)hi.z; a[kk][7] = (_Float16)hi.w;
    }
    __syncthreads();
    floatx4 zero4 = {0.0f, 0.0f, 0.0f, 0.0f};
    floatx4 acc[8];
#pragma unroll
    for (int ct = 0; ct < 8; ++ct) acc[ct] = zero4;
#pragma unroll
    for (int kk = 0; kk < 4; ++kk) {
#pragma unroll
        for (int ct = 0; ct < 8; ++ct) {
            half8 b = *(const half8*)&Wf[kk][ct][lane][0];
            acc[ct] = __builtin_amdgcn_mfma_f32_16x16x32_f16(a[kk], b, acc[ct], 0, 0, 0);
        }
    }
    int orow0 = rbase + wid * 16 + kgrp * 4;
#pragma unroll
    for (int ct = 0; ct < 8; ++ct) {
#pragma unroll
        for (int i = 0; i < 4; ++i) {
            int row = orow0 + i;
            if (row < rows) {
                _Float16 hv = (_Float16)acc[ct][i];
                outb[(size_t)row * HDIM + ct * 16 + lrow] = *(ushort_t*)&hv;
            }
        }
    }
}

// Fused top-K pipeline with padded sync slots + load-based polling.
__global__ __launch_bounds__(256) void topk_fused_k(const float* __restrict__ h,
        const float* __restrict__ pn, float* __restrict__ score, u64* __restrict__ key,
        SelState* st, u32* __restrict__ ghist, int* __restrict__ sync,
        int2* __restrict__ pinfo, int* __restrict__ n2o,
        const int* __restrict__ rowptr, const int* __restrict__ csr,
        float* __restrict__ dinvp, float* __restrict__ hp) {
    __shared__ u32 lh[4096];
    __shared__ u32 sct[256];
    __shared__ u64 spref;
    __shared__ int skrem;
    __shared__ int lastf;
    int t = threadIdx.x;
    int lane = t & 63;
    int gw = blockIdx.x * 4 + (t >> 6);

    // phase 1: scores + keys
    float pnl = pn[lane], pnh = pn[lane + 64];
    for (int node = gw; node < N_NODES; node += TK_BLOCKS * 4) {
        const float* row = h + (size_t)node * HDIM;
        float sv = fmaxf(row[lane], 0.f) * pnl + fmaxf(row[lane+64], 0.f) * pnh;
#pragma unroll
        for (int o = 32; o > 0; o >>= 1) sv += __shfl_xor(sv, o, 64);
        if (lane == 0) {
            score[node] = sv;
            u32 u = __float_as_uint(sv);
            u = (u & 0x80000000u) ? ~u : (u | 0x80000000u);
            key[node] = ((u64)u << 16) | (u64)(65535 - node);
        }
    }
    // barrier 0 (phase1 -> radix)
    __syncthreads();
    if (t == 0) {
        __threadfence();
        int v = atomicAdd(&sync[0 * SYNC_SLOT], 1);
        if (v == TK_BLOCKS - 1) atomicExch(&sync[0 * SYNC_SLOT + 32], 1);
        else while (agent_load(&sync[0 * SYNC_SLOT + 32]) == 0) __builtin_amdgcn_s_sleep(32);
    }
    __syncthreads();
    __threadfence();

    // 4 radix passes, 12-bit digits
    for (int pass = 0; pass < 4; ++pass) {
        int dsh = 36 - 12 * pass;
        if (t == 0) spref = __hip_atomic_load((unsigned long long*)&st->prefix,
                                __ATOMIC_RELAXED, __HIP_MEMORY_SCOPE_AGENT);
        __syncthreads();
        u64 pref = spref;
        for (int b = t; b < 4096; b += 256) lh[b] = 0;
        __syncthreads();
        for (int i = blockIdx.x * 256 + t; i < N_NODES; i += TK_BLOCKS * 256) {
            u64 k = key[i];
            if (((k ^ pref) >> (dsh + 12)) == 0)
                atomicAdd(&lh[(int)((k >> dsh) & 4095)], 1u);
        }
        __syncthreads();
        for (int b = t; b < 4096; b += 256) {
            u32 v = lh[b];
            if (v) atomicAdd(&ghist[pass * 4096 + b], v);
        }
        __threadfence();
        if (t == 0) {
            int v = atomicAdd(&sync[(1 + pass) * SYNC_SLOT], 1);
            lastf = (v == TK_BLOCKS - 1) ? 1 : 0;
        }
        __syncthreads();
        if (lastf) {
            for (int b = t; b < 4096; b += 256)
                lh[b] = agent_load_u32(&ghist[pass * 4096 + b]);
            if (t == 0) skrem = agent_load(&st->krem);
            __syncthreads();
            int krem = skrem;
            u32 ctt = 0;
#pragma unroll
            for (int j = 0; j < 16; ++j) ctt += lh[t * 16 + j];
            sct[t] = ctt;
            __syncthreads();
            for (int d = 1; d < 256; d <<= 1) {
                u32 add = (t + d < 256) ? sct[t + d] : 0u;
                __syncthreads();
                sct[t] += add;
                __syncthreads();
            }
            u32 incl = sct[t];
            u32 excl = incl - ctt;
            if ((int)excl < krem && (int)incl >= krem) {
                u32 run = excl;
                int bsel = 0; u32 csel = 0;
                for (int j = 15; j >= 0; --j) {
                    u32 c = lh[t * 16 + j];
                    run += c;
                    if ((int)run >= krem) { bsel = t * 16 + j; csel = c; break; }
                }
                int newk = krem - (int)(run - csel);
                atomicExch((unsigned long long*)&st->prefix, spref | ((u64)bsel << dsh));
                atomicExch(&st->krem, newk);
            }
            __syncthreads();
            __threadfence();
            if (t == 0) atomicExch(&sync[(1 + pass) * SYNC_SLOT + 32], 1);
        } else {
            if (t == 0) while (agent_load(&sync[(1 + pass) * SYNC_SLOT + 32]) == 0)
                __builtin_amdgcn_s_sleep(32);
        }
        __syncthreads();
        __threadfence();
    }

    // select phase
    if (t == 0) spref = __hip_atomic_load((unsigned long long*)&st->prefix,
                            __ATOMIC_RELAXED, __HIP_MEMORY_SCOPE_AGENT);
    __syncthreads();
    u64 pref = spref;
    for (int i = blockIdx.x * 256 + t; i < N_NODES; i += TK_BLOCKS * 256) {
        if (key[i] >= pref) {
            int pos = atomicAdd(&st->cnt, 1);
            pinfo[i].x = pos;
            n2o[pos] = i;
        } else {
            pinfo[i].x = -1;
        }
    }
    // barrier 5 (select -> hp/pool_deg)
    __syncthreads();
    if (t == 0) {
        __threadfence();
        int v = atomicAdd(&sync[5 * SYNC_SLOT], 1);
        if (v == TK_BLOCKS - 1) atomicExch(&sync[5 * SYNC_SLOT + 32], 1);
        else while (agent_load(&sync[5 * SYNC_SLOT + 32]) == 0) __builtin_amdgcn_s_sleep(32);
    }
    __syncthreads();
    __threadfence();

    // phase 4: hp + pooled degree + dinvp + pinfo.dv
    for (int k = gw; k < KSEL; k += TK_BLOCKS * 4) {
        int old = n2o[k];
        float tv = tanhf(score[old]);
        const float* row = h + (size_t)old * HDIM;
        hp[(size_t)k * HDIM + lane]      = fmaxf(row[lane], 0.f) * tv;
        hp[(size_t)k * HDIM + lane + 64] = fmaxf(row[lane+64], 0.f) * tv;
        int rs = rowptr[old], re = rowptr[old + 1];
        int cnt = 0;
        for (int base = rs; base < re; base += 64) {
            int span = min(64, re - base);
            bool sel = false;
            if (lane < span) sel = (pinfo[csr[base + lane]].x >= 0);
            cnt += __popcll(__ballot(sel));
        }
        if (lane == 0) {
            float dv = rsqrtf((float)cnt + 1.0f);
            dinvp[k] = dv;
            pinfo[old].y = __float_as_int(dv);
        }
    }
}

__global__ __launch_bounds__(256) void pool_stage1_k(const float* __restrict__ h,
        const int* __restrict__ n2o, const int* __restrict__ batch,
        float* __restrict__ partial, int* __restrict__ pcnt) {
    __shared__ float ls[NBATCH * HDIM];
    __shared__ int   lc[NBATCH];
    int t = threadIdx.x;
    for (int i = t; i < NBATCH * HDIM; i += 256) ls[i] = 0.0f;
    if (t < NBATCH) lc[t] = 0;
    __syncthreads();
    int wid = t >> 6, lane = t & 63;
    int start = blockIdx.x * POOL_CHUNK;
    int end = min(start + POOL_CHUNK, KSEL);
    for (int k = start + wid; k < end; k += 4) {
        int b = batch[n2o[k]];
        float2 hv = *(const float2*)&h[(size_t)k * HDIM + 2*lane];
        atomicAdd(&ls[b * HDIM + 2*lane],     fmaxf(hv.x, 0.0f));
        atomicAdd(&ls[b * HDIM + 2*lane + 1], fmaxf(hv.y, 0.0f));
        if (lane == 0) atomicAdd(&lc[b], 1);
    }
    __syncthreads();
    float* pb = partial + (size_t)blockIdx.x * (NBATCH * HDIM);
    for (int i = t; i < NBATCH * HDIM; i += 256) pb[i] = ls[i];
    if (t < NBATCH) pcnt[blockIdx.x * NBATCH + t] = lc[t];
}

__global__ __launch_bounds__(256) void pool_stage2_k(const float* __restrict__ partial,
        const int* __restrict__ pcnt, float* __restrict__ sums, float* __restrict__ cntb) {
    int i = blockIdx.x * 256 + threadIdx.x;
    if (i >= NBATCH * HDIM) return;
    float s = 0.0f;
    for (int p = 0; p < POOL_BLOCKS; ++p) s += partial[(size_t)p * NBATCH * HDIM + i];
    sums[i] = s;
    if (i < NBATCH) {
        int c = 0;
        for (int p = 0; p < POOL_BLOCKS; ++p) c += pcnt[p * NBATCH + i];
        cntb[i] = (float)c;
    }
}

__global__ __launch_bounds__(256) void fc_k(const float* __restrict__ sums,
        const float* __restrict__ cntb, const float* __restrict__ W1b,
        const float* __restrict__ b1b, const float* __restrict__ W2b,
        const float* __restrict__ b2b, float* __restrict__ gbuf,
        float* __restrict__ out, int* done) {
    int t = threadIdx.x;
    int gid = blockIdx.x * 256 + t;
    if (gid < NBATCH * HDIM) {
        int b = gid >> 7, j = gid & 127;
        float inv = 1.0f / fmaxf(cntb[b], 1.0f);
        float acc = 0.0f;
        for (int k = 0; k < HDIM; ++k) acc += sums[b * HDIM + k] * W1b[k * HDIM + j];
        gbuf[gid] = fmaxf(acc * inv + b1b[j], 0.0f);
    }
    __threadfence();
    __shared__ int lastf;
    if (t == 0) lastf = (atomicAdd(done, 1) == (int)gridDim.x - 1) ? 1 : 0;
    __syncthreads();
    if (!lastf || t >= NBATCH) return;
    __threadfence();
    int b = t;
    float l[NCLS];
    for (int c = 0; c < NCLS; ++c) {
        float acc = b2b[c];
        for (int k = 0; k < HDIM; ++k) acc += gbuf[b * HDIM + k] * W2b[k * NCLS + c];
        l[c] = acc;
    }
    float m = fmaxf(l[0], fmaxf(l[1], l[2]));
    float sum = expf(l[0]-m) + expf(l[1]-m) + expf(l[2]-m);
    float ls = logf(sum);
    for (int c = 0; c < NCLS; ++c) out[b * NCLS + c] = l[c] - m - ls;
}

extern "C" void kernel_launch(void* const* d_in, const int* in_sizes, int n_in,
                              void* d_out, int out_size, void* d_ws, size_t ws_size,
                              hipStream_t stream) {
    const float* x    = (const float*)d_in[0];
    const int*   ei   = (const int*)d_in[1];
    const int*   batch= (const int*)d_in[2];
    const float* W1   = (const float*)d_in[3];
    const float* b1   = (const float*)d_in[4];
    const float* W2   = (const float*)d_in[5];
    const float* b2   = (const float*)d_in[6];
    const float* p    = (const float*)d_in[7];
    const float* W3   = (const float*)d_in[8];
    const float* b3   = (const float*)d_in[9];
    const float* W4   = (const float*)d_in[10];
    const float* b4   = (const float*)d_in[11];
    const float* fcW1 = (const float*)d_in[12];
    const float* fcb1 = (const float*)d_in[13];
    const float* fcW2 = (const float*)d_in[14];
    const float* fcb2 = (const float*)d_in[15];
    float* out = (float*)d_out;

    char* ws = (char*)d_ws;
    size_t off = 0;
    auto alloc = [&](size_t bytes) {
        size_t r = off;
        off = (off + bytes + 255) & ~(size_t)255;
        return r;
    };
    float* A     = (float*)(ws + alloc((size_t)N_NODES * HDIM * 4));
    float* Bf    = (float*)(ws + alloc((size_t)N_NODES * HDIM * 4));
    ushort_t* Hbf= (ushort_t*)(ws + alloc((size_t)N_NODES * HDIM * 2));
    u64*   key   = (u64*)  (ws + alloc((size_t)N_NODES * 8));
    float* score = (float*)(ws + alloc((size_t)N_NODES * 4));
    int2*  pinfo = (int2*) (ws + alloc((size_t)N_NODES * 8));
    int*   n2o   = (int*)  (ws + alloc((size_t)KSEL * 4));
    float* pn    = (float*)(ws + alloc(HDIM * 4));
    float* gbuf  = (float*)(ws + alloc(NBATCH * HDIM * 4));
    SelState* st = (SelState*)(ws + alloc(256));
    float* dinv1 = (float*)(ws + alloc((size_t)N_NODES * 4));
    float* dinvp = (float*)(ws + alloc((size_t)KSEL * 4));
    int*   rowptr= (int*)  (ws + alloc((size_t)(N_NODES + 1) * 4));
    int*   csr   = (int*)  (ws + alloc((size_t)N_EDGES * 4));
    u32*   ebuf  = (u32*)  (ws + alloc((size_t)N_EDGES * 4));
    int*   bsum  = (int*)  (ws + alloc(256 * 4));
    int*   boff  = (int*)  (ws + alloc(256 * 4));
    float* partial=(float*)(ws + alloc((size_t)POOL_BLOCKS * NBATCH * HDIM * 4));
    int*   pcnt  = (int*)  (ws + alloc((size_t)POOL_BLOCKS * NBATCH * 4));
    float* sums  = (float*)(ws + alloc(NBATCH * HDIM * 4));
    float* cntb  = (float*)(ws + alloc(NBATCH * 4));
    // zeroed region: degi, gcnt, ghist, sync (padded slots)
    size_t z1 = off;
    int*   degi  = (int*)(ws + alloc((size_t)N_NODES * 4));
    u32*   gcnt  = (u32*)(ws + alloc((size_t)NBUCK * 4));
    u32*   ghist = (u32*)(ws + alloc(4 * 4096 * 4));
    int*   sync  = (int*)(ws + alloc(10 * SYNC_SLOT * 4));
    size_t z1e = off;

    hipMemsetAsync(ws + z1, 0, z1e - z1, stream);
    init_pnorm_k<<<1, HDIM, 0, stream>>>(p, pn, st);

    const int eg   = (N_EDGES + 255) / 256;
    const int ng   = (N_NODES + 255) / 256;
    const int mm_grid_n = (N_NODES + MMB_ROWS - 1) / MMB_ROWS;
    const int mm_grid_k = (KSEL + MMB_ROWS - 1) / MMB_ROWS;
    const int gt_grid_n = (N_NODES + 3) / 4;
    const int gt_grid_k = (KSEL + 3) / 4;

    // full-graph CSR (bucketed build)
    deg_full_k<<<eg, 256, 0, stream>>>(ei, degi);
    scan12_k<<<ng, 256, 0, stream>>>(degi, bsum, boff, dinv1, rowptr, N_NODES, ng,
                                     sync + 8 * SYNC_SLOT);
    scan3_k<<<ng, 256, 0, stream>>>(degi, boff, rowptr, N_NODES);
    csr_bucket_k<<<S1_BLOCKS, 256, 0, stream>>>(ei, rowptr, gcnt, ebuf);
    csr_build_k<<<NBUCK, 256, 0, stream>>>(ebuf, rowptr, csr);

    // conv1 + conv2
    matmul_k<false><<<mm_grid_n, 256, 0, stream>>>(x, W1, Hbf, N_NODES);
    gather_k<<<gt_grid_n, 256, 0, stream>>>(rowptr, csr, dinv1, Hbf, b1, Bf, N_NODES);
    matmul_k<true><<<mm_grid_n, 256, 0, stream>>>(Bf, W2, Hbf, N_NODES);
    gather_k<<<gt_grid_n, 256, 0, stream>>>(rowptr, csr, dinv1, Hbf, b2, Bf, N_NODES);

    // fused top-K pipeline
    topk_fused_k<<<TK_BLOCKS, 256, 0, stream>>>(Bf, pn, score, key, st, ghist, sync,
                                                pinfo, n2o, rowptr, csr, dinvp, A);

    // conv3 + conv4 (pooled, filtered gather over full CSR)
    matmul_k<false><<<mm_grid_k, 256, 0, stream>>>(A, W3, Hbf, KSEL);
    gather_pool_k<<<gt_grid_k, 256, 0, stream>>>(rowptr, csr, n2o, pinfo, dinvp, Hbf, b3, Bf);
    matmul_k<true><<<mm_grid_k, 256, 0, stream>>>(Bf, W4, Hbf, KSEL);
    gather_pool_k<<<gt_grid_k, 256, 0, stream>>>(rowptr, csr, n2o, pinfo, dinvp, Hbf, b4, A);

    // batch mean pool + FC head
    pool_stage1_k<<<POOL_BLOCKS, 256, 0, stream>>>(A, n2o, batch, partial, pcnt);
    pool_stage2_k<<<(NBATCH * HDIM + 255) / 256, 256, 0, stream>>>(partial, pcnt, sums, cntb);
    fc_k<<<(NBATCH * HDIM + 255) / 256, 256, 0, stream>>>(sums, cntb, fcW1, fcb1,
                                                          fcW2, fcb2, gbuf, out,
                                                          sync + 9 * SYNC_SLOT);
}

// Round 18
// 424.081 us; speedup vs baseline: 1.7949x; 1.5978x over previous
//
#include <hip/hip_runtime.h>

#define N_NODES 50000
#define N_EDGES 800000
#define HDIM    128
#define NBATCH  64
#define NCLS    3
#define KSEL    (N_NODES/2)
#define MMB_ROWS 64
#define HIST_BLOCKS 128
#define POOL_BLOCKS 256
#define POOL_CHUNK  ((KSEL + POOL_BLOCKS - 1) / POOL_BLOCKS)
#define NBUCK ((N_NODES + 127) >> 7)
#define EPB   2048
#define S1_BLOCKS ((N_EDGES + EPB - 1) / EPB)
#define SEG_CAP 4096

typedef unsigned long long u64;
typedef unsigned int u32;
typedef unsigned short ushort_t;
typedef _Float16 half8 __attribute__((ext_vector_type(8)));
typedef float floatx4 __attribute__((ext_vector_type(4)));

struct SelState { u64 prefix; int krem; int cnt; };

__device__ __forceinline__ float h2f(ushort_t u) {
    _Float16 h = *(_Float16*)&u;
    return (float)h;
}

__global__ void init_pnorm_k(const float* __restrict__ p, float* __restrict__ pn,
        SelState* st) {
    __shared__ float red[HDIM];
    int t = threadIdx.x;
    float v = p[t];
    red[t] = v * v;
    __syncthreads();
    for (int s = HDIM/2; s > 0; s >>= 1) {
        if (t < s) red[t] += red[t+s];
        __syncthreads();
    }
    pn[t] = v / sqrtf(red[0]);
    if (t == 0) { st->prefix = 0ull; st->krem = KSEL; st->cnt = 0; }
}

__global__ void deg_full_k(const int* __restrict__ ei, int* __restrict__ degi) {
    int e = blockIdx.x * blockDim.x + threadIdx.x;
    if (e >= N_EDGES) return;
    int2 ed = ((const int2*)ei)[e];
    atomicAdd(&degi[ed.y], 1);
}

// fused scan stage1+stage2 (last-block pattern); also computes dinv
__global__ __launch_bounds__(256) void scan12_k(const int* __restrict__ degi,
        int* __restrict__ bsum, int* __restrict__ boff, float* __restrict__ dinv,
        int* __restrict__ rowptr, int n, int nb, int* done) {
    __shared__ int sh[256];
    __shared__ int lastf;
    int t = threadIdx.x;
    int i = blockIdx.x * 256 + t;
    int d = (i < n) ? degi[i] : 0;
    if (i < n) dinv[i] = rsqrtf((float)d + 1.0f);
    sh[t] = d;
    __syncthreads();
    for (int s = 128; s > 0; s >>= 1) {
        if (t < s) sh[t] += sh[t + s];
        __syncthreads();
    }
    if (t == 0) {
        atomicExch(&bsum[blockIdx.x], sh[0]);
        __threadfence();
        int dd = atomicAdd(done, 1);
        lastf = (dd == (int)gridDim.x - 1) ? 1 : 0;
    }
    __syncthreads();
    if (lastf) {
        int v = (t < nb) ? atomicAdd(&bsum[t], 0) : 0;
        sh[t] = v;
        __syncthreads();
        for (int dl = 1; dl < 256; dl <<= 1) {
            int u = (t >= dl) ? sh[t - dl] : 0;
            __syncthreads();
            sh[t] += u;
            __syncthreads();
        }
        if (t < nb) boff[t] = sh[t] - v;
        if (t == 255) rowptr[n] = sh[255];
    }
}

__global__ __launch_bounds__(256) void scan3_k(const int* __restrict__ degi,
        const int* __restrict__ boff, int* __restrict__ rowptr, int n) {
    __shared__ int sh[256];
    int t = threadIdx.x;
    int i = blockIdx.x * 256 + t;
    int v = (i < n) ? degi[i] : 0;
    sh[t] = v;
    __syncthreads();
    for (int d = 1; d < 256; d <<= 1) {
        int u = (t >= d) ? sh[t - d] : 0;
        __syncthreads();
        sh[t] += u;
        __syncthreads();
    }
    if (i < n) rowptr[i] = boff[blockIdx.x] + sh[t] - v;
}

// CSR build stage 1: bucket edges by dst>>7 with block-private consecutive writes.
__global__ __launch_bounds__(256) void csr_bucket_k(const int* __restrict__ ei,
        const int* __restrict__ rowptr, u32* __restrict__ gcnt, u32* __restrict__ ebuf) {
    __shared__ u32 bh[NBUCK];
    __shared__ u32 cursor[NBUCK];
    int t = threadIdx.x;
    for (int i = t; i < NBUCK; i += 256) bh[i] = 0;
    __syncthreads();
    int e0 = blockIdx.x * EPB;
    int2 ed[8]; int nb[8];
#pragma unroll
    for (int i = 0; i < 8; ++i) {
        int e = e0 + t + i * 256;
        if (e < N_EDGES) {
            ed[i] = ((const int2*)ei)[e];
            nb[i] = ed[i].y >> 7;
            atomicAdd(&bh[nb[i]], 1u);
        } else nb[i] = -1;
    }
    __syncthreads();
    for (int b = t; b < NBUCK; b += 256) {
        u32 c = bh[b];
        if (c) cursor[b] = (u32)rowptr[b << 7] + atomicAdd(&gcnt[b], c);
    }
    __syncthreads();
#pragma unroll
    for (int i = 0; i < 8; ++i) {
        if (nb[i] >= 0) {
            u32 pos = atomicAdd(&cursor[nb[i]], 1u);
            ebuf[pos] = ((u32)(ed[i].y & 127) << 16) | (u32)ed[i].x;
        }
    }
}

// CSR build stage 2: block per bucket; scatter segment inside LDS, stream out.
__global__ __launch_bounds__(256) void csr_build_k(const u32* __restrict__ ebuf,
        const int* __restrict__ rowptr, int* __restrict__ csr) {
    __shared__ int rp[129];
    __shared__ int fcnt[128];
    __shared__ int seg[SEG_CAP];
    int b = blockIdx.x;
    int lo = b << 7;
    int nn = min(128, N_NODES - lo);
    int t = threadIdx.x;
    if (t <= nn) rp[t] = rowptr[lo + t];
    if (t < 128) fcnt[t] = 0;
    __syncthreads();
    int segbase = rp[0];
    int segsz = rp[nn] - segbase;
    if (segsz <= SEG_CAP) {
        for (int idx = t; idx < segsz; idx += 256) {
            u32 v = ebuf[segbase + idx];
            int dl = v >> 16;
            int slot = rp[dl] - segbase + atomicAdd(&fcnt[dl], 1);
            seg[slot] = (int)(v & 0xFFFFu);
        }
        __syncthreads();
        for (int idx = t; idx < segsz; idx += 256) csr[segbase + idx] = seg[idx];
    } else {
        for (int idx = t; idx < segsz; idx += 256) {
            u32 v = ebuf[segbase + idx];
            int dl = v >> 16;
            int slot = rp[dl] + atomicAdd(&fcnt[dl], 1);
            csr[slot] = (int)(v & 0xFFFFu);
        }
    }
}

// full-graph gather: out[d] = sum dinv[d]*dinv[src]*h[src] + dinv[d]^2*h[d] + b
__global__ __launch_bounds__(256) void gather_k(const int* __restrict__ rowptr,
        const int* __restrict__ csr, const float* __restrict__ dinv,
        const ushort_t* __restrict__ hb, const float* __restrict__ bias,
        float* __restrict__ out, int n) {
    int node = blockIdx.x * 4 + (threadIdx.x >> 6);
    if (node >= n) return;
    int lane = threadIdx.x & 63;
    float di = dinv[node];
    float2 bv = *(const float2*)&bias[2*lane];
    ushort2 hs = *(const ushort2*)&hb[(size_t)node * HDIM + 2*lane];
    float s2 = di * di;
    float accx = s2 * h2f(hs.x) + bv.x;
    float accy = s2 * h2f(hs.y) + bv.y;
    int rs = rowptr[node], re = rowptr[node + 1];
    for (int base = rs; base < re; base += 64) {
        int cnt = min(64, re - base);
        int srcv = 0; float cv = 0.0f;
        if (lane < cnt) { srcv = csr[base + lane]; cv = di * dinv[srcv]; }
        int j = 0;
        for (; j + 8 <= cnt; j += 8) {
            int s0 = __shfl(srcv, j+0, 64); int s1 = __shfl(srcv, j+1, 64);
            int s2i= __shfl(srcv, j+2, 64); int s3 = __shfl(srcv, j+3, 64);
            int s4 = __shfl(srcv, j+4, 64); int s5 = __shfl(srcv, j+5, 64);
            int s6 = __shfl(srcv, j+6, 64); int s7 = __shfl(srcv, j+7, 64);
            float c0 = __shfl(cv, j+0, 64); float c1 = __shfl(cv, j+1, 64);
            float c2 = __shfl(cv, j+2, 64); float c3 = __shfl(cv, j+3, 64);
            float c4 = __shfl(cv, j+4, 64); float c5 = __shfl(cv, j+5, 64);
            float c6 = __shfl(cv, j+6, 64); float c7 = __shfl(cv, j+7, 64);
            ushort2 v0 = *(const ushort2*)&hb[(size_t)s0 * HDIM + 2*lane];
            ushort2 v1 = *(const ushort2*)&hb[(size_t)s1 * HDIM + 2*lane];
            ushort2 v2 = *(const ushort2*)&hb[(size_t)s2i* HDIM + 2*lane];
            ushort2 v3 = *(const ushort2*)&hb[(size_t)s3 * HDIM + 2*lane];
            ushort2 v4 = *(const ushort2*)&hb[(size_t)s4 * HDIM + 2*lane];
            ushort2 v5 = *(const ushort2*)&hb[(size_t)s5 * HDIM + 2*lane];
            ushort2 v6 = *(const ushort2*)&hb[(size_t)s6 * HDIM + 2*lane];
            ushort2 v7 = *(const ushort2*)&hb[(size_t)s7 * HDIM + 2*lane];
            accx += c0*h2f(v0.x); accy += c0*h2f(v0.y);
            accx += c1*h2f(v1.x); accy += c1*h2f(v1.y);
            accx += c2*h2f(v2.x); accy += c2*h2f(v2.y);
            accx += c3*h2f(v3.x); accy += c3*h2f(v3.y);
            accx += c4*h2f(v4.x); accy += c4*h2f(v4.y);
            accx += c5*h2f(v5.x); accy += c5*h2f(v5.y);
            accx += c6*h2f(v6.x); accy += c6*h2f(v6.y);
            accx += c7*h2f(v7.x); accy += c7*h2f(v7.y);
        }
        for (; j < cnt; ++j) {
            int src = __shfl(srcv, j, 64);
            float c  = __shfl(cv, j, 64);
            ushort2 sv = *(const ushort2*)&hb[(size_t)src * HDIM + 2*lane];
            accx += c * h2f(sv.x);
            accy += c * h2f(sv.y);
        }
    }
    float2 o; o.x = accx; o.y = accy;
    *(float2*)&out[(size_t)node * HDIM + 2*lane] = o;
}

// pooled gather over FULL csr rows with pinfo filter + per-wave LDS compaction
__global__ __launch_bounds__(256) void gather_pool_k(const int* __restrict__ rowptr,
        const int* __restrict__ csr, const int* __restrict__ n2o,
        const int2* __restrict__ pinfo, const float* __restrict__ dinvp,
        const ushort_t* __restrict__ hb, const float* __restrict__ bias,
        float* __restrict__ out) {
    __shared__ int   sns[4][64];
    __shared__ float scf[4][64];
    int k = blockIdx.x * 4 + (threadIdx.x >> 6);
    if (k >= KSEL) return;
    int wid = threadIdx.x >> 6, lane = threadIdx.x & 63;
    float di = dinvp[k];
    float2 bv = *(const float2*)&bias[2*lane];
    ushort2 hs = *(const ushort2*)&hb[(size_t)k * HDIM + 2*lane];
    float s2 = di * di;
    float accx = s2 * h2f(hs.x) + bv.x;
    float accy = s2 * h2f(hs.y) + bv.y;
    int old = n2o[k];
    int rs = rowptr[old], re = rowptr[old + 1];
    for (int base = rs; base < re; base += 64) {
        int span = min(64, re - base);
        int ns = -1; float dv = 0.0f;
        if (lane < span) {
            int2 pi = pinfo[csr[base + lane]];
            ns = pi.x; dv = __int_as_float(pi.y);
        }
        bool sel = (ns >= 0);
        u64 m = __ballot(sel);
        int rank = __popcll(m & ((1ull << lane) - 1ull));
        if (sel) { sns[wid][rank] = ns; scf[wid][rank] = di * dv; }
        int cnt = __popcll(m);
        __threadfence_block();
        int j = 0;
        for (; j + 8 <= cnt; j += 8) {
            int s0 = sns[wid][j+0]; int s1 = sns[wid][j+1];
            int s2i= sns[wid][j+2]; int s3 = sns[wid][j+3];
            int s4 = sns[wid][j+4]; int s5 = sns[wid][j+5];
            int s6 = sns[wid][j+6]; int s7 = sns[wid][j+7];
            float c0 = scf[wid][j+0]; float c1 = scf[wid][j+1];
            float c2 = scf[wid][j+2]; float c3 = scf[wid][j+3];
            float c4 = scf[wid][j+4]; float c5 = scf[wid][j+5];
            float c6 = scf[wid][j+6]; float c7 = scf[wid][j+7];
            ushort2 v0 = *(const ushort2*)&hb[(size_t)s0 * HDIM + 2*lane];
            ushort2 v1 = *(const ushort2*)&hb[(size_t)s1 * HDIM + 2*lane];
            ushort2 v2 = *(const ushort2*)&hb[(size_t)s2i* HDIM + 2*lane];
            ushort2 v3 = *(const ushort2*)&hb[(size_t)s3 * HDIM + 2*lane];
            ushort2 v4 = *(const ushort2*)&hb[(size_t)s4 * HDIM + 2*lane];
            ushort2 v5 = *(const ushort2*)&hb[(size_t)s5 * HDIM + 2*lane];
            ushort2 v6 = *(const ushort2*)&hb[(size_t)s6 * HDIM + 2*lane];
            ushort2 v7 = *(const ushort2*)&hb[(size_t)s7 * HDIM + 2*lane];
            accx += c0*h2f(v0.x); accy += c0*h2f(v0.y);
            accx += c1*h2f(v1.x); accy += c1*h2f(v1.y);
            accx += c2*h2f(v2.x); accy += c2*h2f(v2.y);
            accx += c3*h2f(v3.x); accy += c3*h2f(v3.y);
            accx += c4*h2f(v4.x); accy += c4*h2f(v4.y);
            accx += c5*h2f(v5.x); accy += c5*h2f(v5.y);
            accx += c6*h2f(v6.x); accy += c6*h2f(v6.y);
            accx += c7*h2f(v7.x); accy += c7*h2f(v7.y);
        }
        for (; j < cnt; ++j) {
            int src = sns[wid][j];
            float c = scf[wid][j];
            ushort2 sv = *(const ushort2*)&hb[(size_t)src * HDIM + 2*lane];
            accx += c * h2f(sv.x);
            accy += c * h2f(sv.y);
        }
    }
    float2 o; o.x = accx; o.y = accy;
    *(float2*)&out[(size_t)k * HDIM + 2*lane] = o;
}

// MFMA f16 matmul (W in LDS in fragment order; A global->registers)
template<bool RELU_IN>
__global__ __launch_bounds__(256) void matmul_k(const float* __restrict__ in,
        const float* __restrict__ W, ushort_t* __restrict__ outb, int rows) {
    __shared__ _Float16 Wf[4][8][64][8];
    int t = threadIdx.x;
    int rbase = blockIdx.x * MMB_ROWS;
    for (int idx = t; idx < HDIM * HDIM; idx += 256) {
        int k = idx >> 7, j = idx & 127;
        int kk = k >> 5, kgrp = (k >> 3) & 3, i = k & 7;
        int ct = j >> 4, lrow = j & 15;
        Wf[kk][ct][kgrp * 16 + lrow][i] = (_Float16)W[idx];
    }
    int wid = t >> 6, lane = t & 63;
    int lrow = lane & 15, kgrp = lane >> 4;
    int arow = rbase + wid * 16 + lrow;
    bool rowok = (arow < rows);
    const float* arp = in + (size_t)(rowok ? arow : 0) * HDIM + kgrp * 8;
    half8 a[4];
#pragma unroll
    for (int kk = 0; kk < 4; ++kk) {
        float4 lo = rowok ? *(const float4*)(arp + kk * 32)     : float4{0,0,0,0};
        float4 hi = rowok ? *(const float4*)(arp + kk * 32 + 4) : float4{0,0,0,0};
        if (RELU_IN) {
            lo.x = fmaxf(lo.x, 0.f); lo.y = fmaxf(lo.y, 0.f);
            lo.z = fmaxf(lo.z, 0.f); lo.w = fmaxf(lo.w, 0.f);
            hi.x = fmaxf(hi.x, 0.f); hi.y = fmaxf(hi.y, 0.f);
            hi.z = fmaxf(hi.z, 0.f); hi.w = fmaxf(hi.w, 0.f);
        }
        a[kk][0] = (_Float16)lo.x; a[kk][1] = (_Float16)lo.y;
        a[kk][2] = (_Float16)lo.z; a[kk][3] = (_Float16)lo.w;
        a[kk][4] = (_Float16)hi.x; a[kk][5] = (_Float16)hi.y;
        a[kk][6] = (_Float16)hi.z; a[kk][7] = (_Float16)hi.w;
    }
    __syncthreads();
    floatx4 zero4 = {0.0f, 0.0f, 0.0f, 0.0f};
    floatx4 acc[8];
#pragma unroll
    for (int ct = 0; ct < 8; ++ct) acc[ct] = zero4;
#pragma unroll
    for (int kk = 0; kk < 4; ++kk) {
#pragma unroll
        for (int ct = 0; ct < 8; ++ct) {
            half8 b = *(const half8*)&Wf[kk][ct][lane][0];
            acc[ct] = __builtin_amdgcn_mfma_f32_16x16x32_f16(a[kk], b, acc[ct], 0, 0, 0);
        }
    }
    int orow0 = rbase + wid * 16 + kgrp * 4;
#pragma unroll
    for (int ct = 0; ct < 8; ++ct) {
#pragma unroll
        for (int i = 0; i < 4; ++i) {
            int row = orow0 + i;
            if (row < rows) {
                _Float16 hv = (_Float16)acc[ct][i];
                outb[(size_t)row * HDIM + ct * 16 + lrow] = *(ushort_t*)&hv;
            }
        }
    }
}

__global__ void score_key_k(const float* __restrict__ h, const float* __restrict__ pn,
        float* __restrict__ score, u64* __restrict__ key) {
    int gid  = blockIdx.x * blockDim.x + threadIdx.x;
    int node = gid >> 6;
    int lane = gid & 63;
    if (node >= N_NODES) return;
    const float* row = h + (size_t)node * HDIM;
    float sv = fmaxf(row[lane], 0.f) * pn[lane] + fmaxf(row[lane+64], 0.f) * pn[lane+64];
#pragma unroll
    for (int o = 32; o > 0; o >>= 1) sv += __shfl_xor(sv, o, 64);
    if (lane == 0) {
        score[node] = sv;
        u32 u = __float_as_uint(sv);
        u = (u & 0x80000000u) ? ~u : (u | 0x80000000u);
        key[node] = ((u64)u << 16) | (u64)(65535 - node);
    }
}

// fused LDS-privatized histogram + last-block scan
__global__ __launch_bounds__(256) void histscan_k(const u64* __restrict__ key,
        SelState* st, u32* __restrict__ hist, int pass, int* done) {
    __shared__ u32 lh[256];
    __shared__ int lastf;
    int t = threadIdx.x;
    lh[t] = 0;
    __syncthreads();
    int dsh = 40 - 8 * pass;
    u64 pref = st->prefix;
    for (int i = blockIdx.x * 256 + t; i < N_NODES; i += HIST_BLOCKS * 256) {
        u64 k = key[i];
        if (((k ^ pref) >> (dsh + 8)) == 0)
            atomicAdd(&lh[(int)((k >> dsh) & 255)], 1u);
    }
    __syncthreads();
    u32 v = lh[t];
    if (v) atomicAdd(&hist[pass * 256 + t], v);
    __threadfence();
    __syncthreads();
    if (t == 0) {
        int dd = atomicAdd(done, 1);
        lastf = (dd == HIST_BLOCKS - 1) ? 1 : 0;
    }
    __syncthreads();
    if (lastf) {
        lh[t] = atomicAdd(&hist[pass * 256 + t], 0u);
        __syncthreads();
        if (t == 0) {
            int krem = st->krem;
            int b = 255;
            for (; b > 0; --b) {
                int cnt = (int)lh[b];
                if (cnt < krem) krem -= cnt;
                else break;
            }
            st->prefix |= ((u64)b) << dsh;
            st->krem = krem;
        }
    }
}

__global__ void select_k(const u64* __restrict__ key, SelState* st,
        int2* __restrict__ pinfo, int* __restrict__ n2o) {
    int i = blockIdx.x * blockDim.x + threadIdx.x;
    if (i >= N_NODES) return;
    if (key[i] >= st->prefix) {
        int pos = atomicAdd(&st->cnt, 1);
        pinfo[i].x = pos;
        n2o[pos] = i;
    } else {
        pinfo[i].x = -1;
    }
}

__global__ void hp_k(const float* __restrict__ h2, const float* __restrict__ score,
        const int* __restrict__ n2o, float* __restrict__ hp) {
    int gid = blockIdx.x * blockDim.x + threadIdx.x;
    if (gid >= KSEL * 32) return;
    int k  = gid >> 5;
    int c4 = (gid & 31) << 2;
    int old = n2o[k];
    float tv = tanhf(score[old]);
    float4 hv = *(const float4*)&h2[(size_t)old * HDIM + c4];
    float4 o;
    o.x = fmaxf(hv.x, 0.f) * tv;
    o.y = fmaxf(hv.y, 0.f) * tv;
    o.z = fmaxf(hv.z, 0.f) * tv;
    o.w = fmaxf(hv.w, 0.f) * tv;
    *(float4*)&hp[(size_t)k * HDIM + c4] = o;
}

// pooled degree + dinvp + pinfo.dv
__global__ __launch_bounds__(256) void pool_deg_k(const int* __restrict__ rowptr,
        const int* __restrict__ csr, const int* __restrict__ n2o,
        int2* __restrict__ pinfo, float* __restrict__ dinvp) {
    int k = blockIdx.x * 4 + (threadIdx.x >> 6);
    if (k >= KSEL) return;
    int lane = threadIdx.x & 63;
    int old = n2o[k];
    int rs = rowptr[old], re = rowptr[old + 1];
    int cnt = 0;
    for (int base = rs; base < re; base += 64) {
        int span = min(64, re - base);
        bool sel = false;
        if (lane < span) sel = (pinfo[csr[base + lane]].x >= 0);
        cnt += __popcll(__ballot(sel));
    }
    if (lane == 0) {
        float dv = rsqrtf((float)cnt + 1.0f);
        dinvp[k] = dv;
        pinfo[old].y = __float_as_int(dv);
    }
}

__global__ __launch_bounds__(256) void pool_stage1_k(const float* __restrict__ h,
        const int* __restrict__ n2o, const int* __restrict__ batch,
        float* __restrict__ partial, int* __restrict__ pcnt) {
    __shared__ float ls[NBATCH * HDIM];
    __shared__ int   lc[NBATCH];
    int t = threadIdx.x;
    for (int i = t; i < NBATCH * HDIM; i += 256) ls[i] = 0.0f;
    if (t < NBATCH) lc[t] = 0;
    __syncthreads();
    int wid = t >> 6, lane = t & 63;
    int start = blockIdx.x * POOL_CHUNK;
    int end = min(start + POOL_CHUNK, KSEL);
    for (int k = start + wid; k < end; k += 4) {
        int b = batch[n2o[k]];
        float2 hv = *(const float2*)&h[(size_t)k * HDIM + 2*lane];
        atomicAdd(&ls[b * HDIM + 2*lane],     fmaxf(hv.x, 0.0f));
        atomicAdd(&ls[b * HDIM + 2*lane + 1], fmaxf(hv.y, 0.0f));
        if (lane == 0) atomicAdd(&lc[b], 1);
    }
    __syncthreads();
    float* pb = partial + (size_t)blockIdx.x * (NBATCH * HDIM);
    for (int i = t; i < NBATCH * HDIM; i += 256) pb[i] = ls[i];
    if (t < NBATCH) pcnt[blockIdx.x * NBATCH + t] = lc[t];
}

__global__ __launch_bounds__(256) void pool_stage2_k(const float* __restrict__ partial,
        const int* __restrict__ pcnt, float* __restrict__ sums, float* __restrict__ cntb) {
    int i = blockIdx.x * 256 + threadIdx.x;
    if (i >= NBATCH * HDIM) return;
    float s = 0.0f;
    for (int p = 0; p < POOL_BLOCKS; ++p) s += partial[(size_t)p * NBATCH * HDIM + i];
    sums[i] = s;
    if (i < NBATCH) {
        int c = 0;
        for (int p = 0; p < POOL_BLOCKS; ++p) c += pcnt[p * NBATCH + i];
        cntb[i] = (float)c;
    }
}

// fc1 (grid) + fc2/log_softmax (last block)
__global__ __launch_bounds__(256) void fc_k(const float* __restrict__ sums,
        const float* __restrict__ cntb, const float* __restrict__ W1b,
        const float* __restrict__ b1b, const float* __restrict__ W2b,
        const float* __restrict__ b2b, float* __restrict__ gbuf,
        float* __restrict__ out, int* done) {
    int t = threadIdx.x;
    int gid = blockIdx.x * 256 + t;
    if (gid < NBATCH * HDIM) {
        int b = gid >> 7, j = gid & 127;
        float inv = 1.0f / fmaxf(cntb[b], 1.0f);
        float acc = 0.0f;
        for (int k = 0; k < HDIM; ++k) acc += sums[b * HDIM + k] * W1b[k * HDIM + j];
        gbuf[gid] = fmaxf(acc * inv + b1b[j], 0.0f);
    }
    __threadfence();
    __shared__ int lastf;
    if (t == 0) lastf = (atomicAdd(done, 1) == (int)gridDim.x - 1) ? 1 : 0;
    __syncthreads();
    if (!lastf || t >= NBATCH) return;
    __threadfence();
    int b = t;
    float l[NCLS];
    for (int c = 0; c < NCLS; ++c) {
        float acc = b2b[c];
        for (int k = 0; k < HDIM; ++k) acc += gbuf[b * HDIM + k] * W2b[k * NCLS + c];
        l[c] = acc;
    }
    float m = fmaxf(l[0], fmaxf(l[1], l[2]));
    float sum = expf(l[0]-m) + expf(l[1]-m) + expf(l[2]-m);
    float ls = logf(sum);
    for (int c = 0; c < NCLS; ++c) out[b * NCLS + c] = l[c] - m - ls;
}

extern "C" void kernel_launch(void* const* d_in, const int* in_sizes, int n_in,
                              void* d_out, int out_size, void* d_ws, size_t ws_size,
                              hipStream_t stream) {
    const float* x    = (const float*)d_in[0];
    const int*   ei   = (const int*)d_in[1];
    const int*   batch= (const int*)d_in[2];
    const float* W1   = (const float*)d_in[3];
    const float* b1   = (const float*)d_in[4];
    const float* W2   = (const float*)d_in[5];
    const float* b2   = (const float*)d_in[6];
    const float* p    = (const float*)d_in[7];
    const float* W3   = (const float*)d_in[8];
    const float* b3   = (const float*)d_in[9];
    const float* W4   = (const float*)d_in[10];
    const float* b4   = (const float*)d_in[11];
    const float* fcW1 = (const float*)d_in[12];
    const float* fcb1 = (const float*)d_in[13];
    const float* fcW2 = (const float*)d_in[14];
    const float* fcb2 = (const float*)d_in[15];
    float* out = (float*)d_out;

    char* ws = (char*)d_ws;
    size_t off = 0;
    auto alloc = [&](size_t bytes) {
        size_t r = off;
        off = (off + bytes + 255) & ~(size_t)255;
        return r;
    };
    float* A     = (float*)(ws + alloc((size_t)N_NODES * HDIM * 4));
    float* Bf    = (float*)(ws + alloc((size_t)N_NODES * HDIM * 4));
    ushort_t* Hbf= (ushort_t*)(ws + alloc((size_t)N_NODES * HDIM * 2));
    u64*   key   = (u64*)  (ws + alloc((size_t)N_NODES * 8));
    float* score = (float*)(ws + alloc((size_t)N_NODES * 4));
    int2*  pinfo = (int2*) (ws + alloc((size_t)N_NODES * 8));
    int*   n2o   = (int*)  (ws + alloc((size_t)KSEL * 4));
    float* pn    = (float*)(ws + alloc(HDIM * 4));
    float* gbuf  = (float*)(ws + alloc(NBATCH * HDIM * 4));
    SelState* st = (SelState*)(ws + alloc(256));
    float* dinv1 = (float*)(ws + alloc((size_t)N_NODES * 4));
    float* dinvp = (float*)(ws + alloc((size_t)KSEL * 4));
    int*   rowptr= (int*)  (ws + alloc((size_t)(N_NODES + 1) * 4));
    int*   csr   = (int*)  (ws + alloc((size_t)N_EDGES * 4));
    u32*   ebuf  = (u32*)  (ws + alloc((size_t)N_EDGES * 4));
    int*   bsum  = (int*)  (ws + alloc(256 * 4));
    int*   boff  = (int*)  (ws + alloc(256 * 4));
    float* partial=(float*)(ws + alloc((size_t)POOL_BLOCKS * NBATCH * HDIM * 4));
    int*   pcnt  = (int*)  (ws + alloc((size_t)POOL_BLOCKS * NBATCH * 4));
    float* sums  = (float*)(ws + alloc(NBATCH * HDIM * 4));
    float* cntb  = (float*)(ws + alloc(NBATCH * 4));
    // zeroed region: degi, gcnt, hist, done
    size_t z1 = off;
    int*   degi  = (int*)(ws + alloc((size_t)N_NODES * 4));
    u32*   gcnt  = (u32*)(ws + alloc((size_t)NBUCK * 4));
    u32*   hist  = (u32*)(ws + alloc(6 * 256 * 4));
    int*   done  = (int*)(ws + alloc(16 * 4));
    size_t z1e = off;

    hipMemsetAsync(ws + z1, 0, z1e - z1, stream);
    init_pnorm_k<<<1, HDIM, 0, stream>>>(p, pn, st);

    const int eg   = (N_EDGES + 255) / 256;
    const int ng   = (N_NODES + 255) / 256;
    const int mm_grid_n = (N_NODES + MMB_ROWS - 1) / MMB_ROWS;
    const int mm_grid_k = (KSEL + MMB_ROWS - 1) / MMB_ROWS;
    const int gt_grid_n = (N_NODES + 3) / 4;
    const int gt_grid_k = (KSEL + 3) / 4;
    const int kh4_grid  = (KSEL * 32 + 255) / 256;

    // full-graph CSR (bucketed, write-amp-free)
    deg_full_k<<<eg, 256, 0, stream>>>(ei, degi);
    scan12_k<<<ng, 256, 0, stream>>>(degi, bsum, boff, dinv1, rowptr, N_NODES, ng, done + 0);
    scan3_k<<<ng, 256, 0, stream>>>(degi, boff, rowptr, N_NODES);
    csr_bucket_k<<<S1_BLOCKS, 256, 0, stream>>>(ei, rowptr, gcnt, ebuf);
    csr_build_k<<<NBUCK, 256, 0, stream>>>(ebuf, rowptr, csr);

    // conv1: Bf = gcn(x, W1, b1)
    matmul_k<false><<<mm_grid_n, 256, 0, stream>>>(x, W1, Hbf, N_NODES);
    gather_k<<<gt_grid_n, 256, 0, stream>>>(rowptr, csr, dinv1, Hbf, b1, Bf, N_NODES);
    // conv2: Bf = gcn(relu(Bf), W2, b2)
    matmul_k<true><<<mm_grid_n, 256, 0, stream>>>(Bf, W2, Hbf, N_NODES);
    gather_k<<<gt_grid_n, 256, 0, stream>>>(rowptr, csr, dinv1, Hbf, b2, Bf, N_NODES);

    // score + exact top-K
    score_key_k<<<(N_NODES * 64 + 255) / 256, 256, 0, stream>>>(Bf, pn, score, key);
    for (int pass = 0; pass < 6; ++pass)
        histscan_k<<<HIST_BLOCKS, 256, 0, stream>>>(key, st, hist, pass, done + 2 + pass);
    select_k<<<ng, 256, 0, stream>>>(key, st, pinfo, n2o);
    hp_k<<<kh4_grid, 256, 0, stream>>>(Bf, score, n2o, A);

    // pooled degrees + dinvp + pinfo.dv (no pooled CSR build)
    pool_deg_k<<<gt_grid_k, 256, 0, stream>>>(rowptr, csr, n2o, pinfo, dinvp);

    // conv3: Bf = gcn(hp(=A), W3, b3)
    matmul_k<false><<<mm_grid_k, 256, 0, stream>>>(A, W3, Hbf, KSEL);
    gather_pool_k<<<gt_grid_k, 256, 0, stream>>>(rowptr, csr, n2o, pinfo, dinvp, Hbf, b3, Bf);
    // conv4: A = gcn(relu(Bf), W4, b4)
    matmul_k<true><<<mm_grid_k, 256, 0, stream>>>(Bf, W4, Hbf, KSEL);
    gather_pool_k<<<gt_grid_k, 256, 0, stream>>>(rowptr, csr, n2o, pinfo, dinvp, Hbf, b4, A);

    // batch mean pool + FC head (fc2 fused as last-block)
    pool_stage1_k<<<POOL_BLOCKS, 256, 0, stream>>>(A, n2o, batch, partial, pcnt);
    pool_stage2_k<<<(NBATCH * HDIM + 255) / 256, 256, 0, stream>>>(partial, pcnt, sums, cntb);
    fc_k<<<(NBATCH * HDIM + 255) / 256, 256, 0, stream>>>(sums, cntb, fcW1, fcb1,
                                                          fcW2, fcb2, gbuf, out, done + 8);
}

// Round 19
// 377.002 us; speedup vs baseline: 2.0190x; 1.1249x over previous
//
#include <hip/hip_runtime.h>

#define N_NODES 50000
#define N_EDGES 800000
#define HDIM    128
#define NBATCH  64
#define NCLS    3
#define KSEL    (N_NODES/2)
#define MMB_ROWS 64
#define HIST_BLOCKS 128
#define RBINS 4096
#define POOL_BLOCKS 256
#define POOL_CHUNK  ((KSEL + POOL_BLOCKS - 1) / POOL_BLOCKS)
#define NBUCK ((N_NODES + 127) >> 7)
#define EPB   2048
#define S1_BLOCKS ((N_EDGES + EPB - 1) / EPB)
#define SEG_CAP 4096

typedef unsigned long long u64;
typedef unsigned int u32;
typedef unsigned short ushort_t;
typedef _Float16 half8 __attribute__((ext_vector_type(8)));
typedef float floatx4 __attribute__((ext_vector_type(4)));

struct SelState { u64 prefix; int krem; int cnt; };

__device__ __forceinline__ float h2f(ushort_t u) {
    _Float16 h = *(_Float16*)&u;
    return (float)h;
}

__global__ void init_pnorm_k(const float* __restrict__ p, float* __restrict__ pn,
        SelState* st) {
    __shared__ float red[HDIM];
    int t = threadIdx.x;
    float v = p[t];
    red[t] = v * v;
    __syncthreads();
    for (int s = HDIM/2; s > 0; s >>= 1) {
        if (t < s) red[t] += red[t+s];
        __syncthreads();
    }
    pn[t] = v / sqrtf(red[0]);
    if (t == 0) { st->prefix = 0ull; st->krem = KSEL; st->cnt = 0; }
}

__global__ void deg_full_k(const int* __restrict__ ei, int* __restrict__ degi) {
    int e = blockIdx.x * blockDim.x + threadIdx.x;
    if (e >= N_EDGES) return;
    int2 ed = ((const int2*)ei)[e];
    atomicAdd(&degi[ed.y], 1);
}

// fused scan stage1+stage2 (last-block pattern); also computes dinv
__global__ __launch_bounds__(256) void scan12_k(const int* __restrict__ degi,
        int* __restrict__ bsum, int* __restrict__ boff, float* __restrict__ dinv,
        int* __restrict__ rowptr, int n, int nb, int* done) {
    __shared__ int sh[256];
    __shared__ int lastf;
    int t = threadIdx.x;
    int i = blockIdx.x * 256 + t;
    int d = (i < n) ? degi[i] : 0;
    if (i < n) dinv[i] = rsqrtf((float)d + 1.0f);
    sh[t] = d;
    __syncthreads();
    for (int s = 128; s > 0; s >>= 1) {
        if (t < s) sh[t] += sh[t + s];
        __syncthreads();
    }
    if (t == 0) {
        atomicExch(&bsum[blockIdx.x], sh[0]);
        __threadfence();
        int dd = atomicAdd(done, 1);
        lastf = (dd == (int)gridDim.x - 1) ? 1 : 0;
    }
    __syncthreads();
    if (lastf) {
        int v = (t < nb) ? atomicAdd(&bsum[t], 0) : 0;
        sh[t] = v;
        __syncthreads();
        for (int dl = 1; dl < 256; dl <<= 1) {
            int u = (t >= dl) ? sh[t - dl] : 0;
            __syncthreads();
            sh[t] += u;
            __syncthreads();
        }
        if (t < nb) boff[t] = sh[t] - v;
        if (t == 255) rowptr[n] = sh[255];
    }
}

__global__ __launch_bounds__(256) void scan3_k(const int* __restrict__ degi,
        const int* __restrict__ boff, int* __restrict__ rowptr, int n) {
    __shared__ int sh[256];
    int t = threadIdx.x;
    int i = blockIdx.x * 256 + t;
    int v = (i < n) ? degi[i] : 0;
    sh[t] = v;
    __syncthreads();
    for (int d = 1; d < 256; d <<= 1) {
        int u = (t >= d) ? sh[t - d] : 0;
        __syncthreads();
        sh[t] += u;
        __syncthreads();
    }
    if (i < n) rowptr[i] = boff[blockIdx.x] + sh[t] - v;
}

// CSR build stage 1: bucket edges by dst>>7 with block-private consecutive writes.
__global__ __launch_bounds__(256) void csr_bucket_k(const int* __restrict__ ei,
        const int* __restrict__ rowptr, u32* __restrict__ gcnt, u32* __restrict__ ebuf) {
    __shared__ u32 bh[NBUCK];
    __shared__ u32 cursor[NBUCK];
    int t = threadIdx.x;
    for (int i = t; i < NBUCK; i += 256) bh[i] = 0;
    __syncthreads();
    int e0 = blockIdx.x * EPB;
    int2 ed[8]; int nb[8];
#pragma unroll
    for (int i = 0; i < 8; ++i) {
        int e = e0 + t + i * 256;
        if (e < N_EDGES) {
            ed[i] = ((const int2*)ei)[e];
            nb[i] = ed[i].y >> 7;
            atomicAdd(&bh[nb[i]], 1u);
        } else nb[i] = -1;
    }
    __syncthreads();
    for (int b = t; b < NBUCK; b += 256) {
        u32 c = bh[b];
        if (c) cursor[b] = (u32)rowptr[b << 7] + atomicAdd(&gcnt[b], c);
    }
    __syncthreads();
#pragma unroll
    for (int i = 0; i < 8; ++i) {
        if (nb[i] >= 0) {
            u32 pos = atomicAdd(&cursor[nb[i]], 1u);
            ebuf[pos] = ((u32)(ed[i].y & 127) << 16) | (u32)ed[i].x;
        }
    }
}

// CSR build stage 2: block per bucket; scatter segment inside LDS, stream out.
__global__ __launch_bounds__(256) void csr_build_k(const u32* __restrict__ ebuf,
        const int* __restrict__ rowptr, int* __restrict__ csr) {
    __shared__ int rp[129];
    __shared__ int fcnt[128];
    __shared__ int seg[SEG_CAP];
    int b = blockIdx.x;
    int lo = b << 7;
    int nn = min(128, N_NODES - lo);
    int t = threadIdx.x;
    if (t <= nn) rp[t] = rowptr[lo + t];
    if (t < 128) fcnt[t] = 0;
    __syncthreads();
    int segbase = rp[0];
    int segsz = rp[nn] - segbase;
    if (segsz <= SEG_CAP) {
        for (int idx = t; idx < segsz; idx += 256) {
            u32 v = ebuf[segbase + idx];
            int dl = v >> 16;
            int slot = rp[dl] - segbase + atomicAdd(&fcnt[dl], 1);
            seg[slot] = (int)(v & 0xFFFFu);
        }
        __syncthreads();
        for (int idx = t; idx < segsz; idx += 256) csr[segbase + idx] = seg[idx];
    } else {
        for (int idx = t; idx < segsz; idx += 256) {
            u32 v = ebuf[segbase + idx];
            int dl = v >> 16;
            int slot = rp[dl] + atomicAdd(&fcnt[dl], 1);
            csr[slot] = (int)(v & 0xFFFFu);
        }
    }
}

// full-graph gather; SCORE=true also emits score+key from the registers.
template<bool SCORE>
__global__ __launch_bounds__(256) void gather_k(const int* __restrict__ rowptr,
        const int* __restrict__ csr, const float* __restrict__ dinv,
        const ushort_t* __restrict__ hb, const float* __restrict__ bias,
        float* __restrict__ out, int n, const float* __restrict__ pn,
        float* __restrict__ score, u64* __restrict__ keyv) {
    int node = blockIdx.x * 4 + (threadIdx.x >> 6);
    if (node >= n) return;
    int lane = threadIdx.x & 63;
    float di = dinv[node];
    float2 bv = *(const float2*)&bias[2*lane];
    ushort2 hs = *(const ushort2*)&hb[(size_t)node * HDIM + 2*lane];
    float s2 = di * di;
    float accx = s2 * h2f(hs.x) + bv.x;
    float accy = s2 * h2f(hs.y) + bv.y;
    int rs = rowptr[node], re = rowptr[node + 1];
    for (int base = rs; base < re; base += 64) {
        int cnt = min(64, re - base);
        int srcv = 0; float cv = 0.0f;
        if (lane < cnt) { srcv = csr[base + lane]; cv = di * dinv[srcv]; }
        int j = 0;
        for (; j + 8 <= cnt; j += 8) {
            int s0 = __shfl(srcv, j+0, 64); int s1 = __shfl(srcv, j+1, 64);
            int s2i= __shfl(srcv, j+2, 64); int s3 = __shfl(srcv, j+3, 64);
            int s4 = __shfl(srcv, j+4, 64); int s5 = __shfl(srcv, j+5, 64);
            int s6 = __shfl(srcv, j+6, 64); int s7 = __shfl(srcv, j+7, 64);
            float c0 = __shfl(cv, j+0, 64); float c1 = __shfl(cv, j+1, 64);
            float c2 = __shfl(cv, j+2, 64); float c3 = __shfl(cv, j+3, 64);
            float c4 = __shfl(cv, j+4, 64); float c5 = __shfl(cv, j+5, 64);
            float c6 = __shfl(cv, j+6, 64); float c7 = __shfl(cv, j+7, 64);
            ushort2 v0 = *(const ushort2*)&hb[(size_t)s0 * HDIM + 2*lane];
            ushort2 v1 = *(const ushort2*)&hb[(size_t)s1 * HDIM + 2*lane];
            ushort2 v2 = *(const ushort2*)&hb[(size_t)s2i* HDIM + 2*lane];
            ushort2 v3 = *(const ushort2*)&hb[(size_t)s3 * HDIM + 2*lane];
            ushort2 v4 = *(const ushort2*)&hb[(size_t)s4 * HDIM + 2*lane];
            ushort2 v5 = *(const ushort2*)&hb[(size_t)s5 * HDIM + 2*lane];
            ushort2 v6 = *(const ushort2*)&hb[(size_t)s6 * HDIM + 2*lane];
            ushort2 v7 = *(const ushort2*)&hb[(size_t)s7 * HDIM + 2*lane];
            accx += c0*h2f(v0.x); accy += c0*h2f(v0.y);
            accx += c1*h2f(v1.x); accy += c1*h2f(v1.y);
            accx += c2*h2f(v2.x); accy += c2*h2f(v2.y);
            accx += c3*h2f(v3.x); accy += c3*h2f(v3.y);
            accx += c4*h2f(v4.x); accy += c4*h2f(v4.y);
            accx += c5*h2f(v5.x); accy += c5*h2f(v5.y);
            accx += c6*h2f(v6.x); accy += c6*h2f(v6.y);
            accx += c7*h2f(v7.x); accy += c7*h2f(v7.y);
        }
        for (; j < cnt; ++j) {
            int src = __shfl(srcv, j, 64);
            float c  = __shfl(cv, j, 64);
            ushort2 sv = *(const ushort2*)&hb[(size_t)src * HDIM + 2*lane];
            accx += c * h2f(sv.x);
            accy += c * h2f(sv.y);
        }
    }
    float2 o; o.x = accx; o.y = accy;
    *(float2*)&out[(size_t)node * HDIM + 2*lane] = o;
    if (SCORE) {
        float2 pv = *(const float2*)&pn[2*lane];
        float sv = fmaxf(accx, 0.f) * pv.x + fmaxf(accy, 0.f) * pv.y;
#pragma unroll
        for (int os = 32; os > 0; os >>= 1) sv += __shfl_xor(sv, os, 64);
        if (lane == 0) {
            score[node] = sv;
            u32 u = __float_as_uint(sv);
            u = (u & 0x80000000u) ? ~u : (u | 0x80000000u);
            keyv[node] = ((u64)u << 16) | (u64)(65535 - node);
        }
    }
}

// pooled gather over FULL csr rows with pinfo filter + per-wave LDS compaction
__global__ __launch_bounds__(256) void gather_pool_k(const int* __restrict__ rowptr,
        const int* __restrict__ csr, const int* __restrict__ n2o,
        const int2* __restrict__ pinfo, const float* __restrict__ dinvp,
        const ushort_t* __restrict__ hb, const float* __restrict__ bias,
        float* __restrict__ out) {
    __shared__ int   sns[4][64];
    __shared__ float scf[4][64];
    int k = blockIdx.x * 4 + (threadIdx.x >> 6);
    if (k >= KSEL) return;
    int wid = threadIdx.x >> 6, lane = threadIdx.x & 63;
    float di = dinvp[k];
    float2 bv = *(const float2*)&bias[2*lane];
    ushort2 hs = *(const ushort2*)&hb[(size_t)k * HDIM + 2*lane];
    float s2 = di * di;
    float accx = s2 * h2f(hs.x) + bv.x;
    float accy = s2 * h2f(hs.y) + bv.y;
    int old = n2o[k];
    int rs = rowptr[old], re = rowptr[old + 1];
    for (int base = rs; base < re; base += 64) {
        int span = min(64, re - base);
        int ns = -1; float dv = 0.0f;
        if (lane < span) {
            int2 pi = pinfo[csr[base + lane]];
            ns = pi.x; dv = __int_as_float(pi.y);
        }
        bool sel = (ns >= 0);
        u64 m = __ballot(sel);
        int rank = __popcll(m & ((1ull << lane) - 1ull));
        if (sel) { sns[wid][rank] = ns; scf[wid][rank] = di * dv; }
        int cnt = __popcll(m);
        __threadfence_block();
        int j = 0;
        for (; j + 8 <= cnt; j += 8) {
            int s0 = sns[wid][j+0]; int s1 = sns[wid][j+1];
            int s2i= sns[wid][j+2]; int s3 = sns[wid][j+3];
            int s4 = sns[wid][j+4]; int s5 = sns[wid][j+5];
            int s6 = sns[wid][j+6]; int s7 = sns[wid][j+7];
            float c0 = scf[wid][j+0]; float c1 = scf[wid][j+1];
            float c2 = scf[wid][j+2]; float c3 = scf[wid][j+3];
            float c4 = scf[wid][j+4]; float c5 = scf[wid][j+5];
            float c6 = scf[wid][j+6]; float c7 = scf[wid][j+7];
            ushort2 v0 = *(const ushort2*)&hb[(size_t)s0 * HDIM + 2*lane];
            ushort2 v1 = *(const ushort2*)&hb[(size_t)s1 * HDIM + 2*lane];
            ushort2 v2 = *(const ushort2*)&hb[(size_t)s2i* HDIM + 2*lane];
            ushort2 v3 = *(const ushort2*)&hb[(size_t)s3 * HDIM + 2*lane];
            ushort2 v4 = *(const ushort2*)&hb[(size_t)s4 * HDIM + 2*lane];
            ushort2 v5 = *(const ushort2*)&hb[(size_t)s5 * HDIM + 2*lane];
            ushort2 v6 = *(const ushort2*)&hb[(size_t)s6 * HDIM + 2*lane];
            ushort2 v7 = *(const ushort2*)&hb[(size_t)s7 * HDIM + 2*lane];
            accx += c0*h2f(v0.x); accy += c0*h2f(v0.y);
            accx += c1*h2f(v1.x); accy += c1*h2f(v1.y);
            accx += c2*h2f(v2.x); accy += c2*h2f(v2.y);
            accx += c3*h2f(v3.x); accy += c3*h2f(v3.y);
            accx += c4*h2f(v4.x); accy += c4*h2f(v4.y);
            accx += c5*h2f(v5.x); accy += c5*h2f(v5.y);
            accx += c6*h2f(v6.x); accy += c6*h2f(v6.y);
            accx += c7*h2f(v7.x); accy += c7*h2f(v7.y);
        }
        for (; j < cnt; ++j) {
            int src = sns[wid][j];
            float c = scf[wid][j];
            ushort2 sv = *(const ushort2*)&hb[(size_t)src * HDIM + 2*lane];
            accx += c * h2f(sv.x);
            accy += c * h2f(sv.y);
        }
    }
    float2 o; o.x = accx; o.y = accy;
    *(float2*)&out[(size_t)k * HDIM + 2*lane] = o;
}

// MFMA f16 matmul (W in LDS in fragment order; A global->registers)
template<bool RELU_IN>
__global__ __launch_bounds__(256) void matmul_k(const float* __restrict__ in,
        const float* __restrict__ W, ushort_t* __restrict__ outb, int rows) {
    __shared__ _Float16 Wf[4][8][64][8];
    int t = threadIdx.x;
    int rbase = blockIdx.x * MMB_ROWS;
    for (int idx = t; idx < HDIM * HDIM; idx += 256) {
        int k = idx >> 7, j = idx & 127;
        int kk = k >> 5, kgrp = (k >> 3) & 3, i = k & 7;
        int ct = j >> 4, lrow = j & 15;
        Wf[kk][ct][kgrp * 16 + lrow][i] = (_Float16)W[idx];
    }
    int wid = t >> 6, lane = t & 63;
    int lrow = lane & 15, kgrp = lane >> 4;
    int arow = rbase + wid * 16 + lrow;
    bool rowok = (arow < rows);
    const float* arp = in + (size_t)(rowok ? arow : 0) * HDIM + kgrp * 8;
    half8 a[4];
#pragma unroll
    for (int kk = 0; kk < 4; ++kk) {
        float4 lo = rowok ? *(const float4*)(arp + kk * 32)     : float4{0,0,0,0};
        float4 hi = rowok ? *(const float4*)(arp + kk * 32 + 4) : float4{0,0,0,0};
        if (RELU_IN) {
            lo.x = fmaxf(lo.x, 0.f); lo.y = fmaxf(lo.y, 0.f);
            lo.z = fmaxf(lo.z, 0.f); lo.w = fmaxf(lo.w, 0.f);
            hi.x = fmaxf(hi.x, 0.f); hi.y = fmaxf(hi.y, 0.f);
            hi.z = fmaxf(hi.z, 0.f); hi.w = fmaxf(hi.w, 0.f);
        }
        a[kk][0] = (_Float16)lo.x; a[kk][1] = (_Float16)lo.y;
        a[kk][2] = (_Float16)lo.z; a[kk][3] = (_Float16)lo.w;
        a[kk][4] = (_Float16)hi.x; a[kk][5] = (_Float16)hi.y;
        a[kk][6] = (_Float16)hi.z; a[kk][7] = (_Float16)hi.w;
    }
    __syncthreads();
    floatx4 zero4 = {0.0f, 0.0f, 0.0f, 0.0f};
    floatx4 acc[8];
#pragma unroll
    for (int ct = 0; ct < 8; ++ct) acc[ct] = zero4;
#pragma unroll
    for (int kk = 0; kk < 4; ++kk) {
#pragma unroll
        for (int ct = 0; ct < 8; ++ct) {
            half8 b = *(const half8*)&Wf[kk][ct][lane][0];
            acc[ct] = __builtin_amdgcn_mfma_f32_16x16x32_f16(a[kk], b, acc[ct], 0, 0, 0);
        }
    }
    int orow0 = rbase + wid * 16 + kgrp * 4;
#pragma unroll
    for (int ct = 0; ct < 8; ++ct) {
#pragma unroll
        for (int i = 0; i < 4; ++i) {
            int row = orow0 + i;
            if (row < rows) {
                _Float16 hv = (_Float16)acc[ct][i];
                outb[(size_t)row * HDIM + ct * 16 + lrow] = *(ushort_t*)&hv;
            }
        }
    }
}

// 12-bit radix pass: LDS-privatized 4096-bin histogram + last-block straddle scan.
__global__ __launch_bounds__(256) void histscan_k(const u64* __restrict__ key,
        SelState* st, u32* __restrict__ hist, int pass, int* done) {
    __shared__ u32 lh[RBINS];
    __shared__ u32 sct[256];
    __shared__ int lastf;
    int t = threadIdx.x;
    for (int b = t; b < RBINS; b += 256) lh[b] = 0;
    __syncthreads();
    int dsh = 36 - 12 * pass;
    u64 pref = st->prefix;
    for (int i = blockIdx.x * 256 + t; i < N_NODES; i += HIST_BLOCKS * 256) {
        u64 k = key[i];
        if (((k ^ pref) >> (dsh + 12)) == 0)
            atomicAdd(&lh[(int)((k >> dsh) & 4095)], 1u);
    }
    __syncthreads();
    for (int b = t; b < RBINS; b += 256) {
        u32 v = lh[b];
        if (v) atomicAdd(&hist[pass * RBINS + b], v);
    }
    __threadfence();
    __syncthreads();
    if (t == 0) {
        int dd = atomicAdd(done, 1);
        lastf = (dd == HIST_BLOCKS - 1) ? 1 : 0;
    }
    __syncthreads();
    if (lastf) {
        for (int b = t; b < RBINS; b += 256)
            lh[b] = atomicAdd(&hist[pass * RBINS + b], 0u);
        __syncthreads();
        int krem = st->krem;
        u32 ctt = 0;
#pragma unroll
        for (int j = 0; j < 16; ++j) ctt += lh[t * 16 + j];
        sct[t] = ctt;
        __syncthreads();
        for (int d = 1; d < 256; d <<= 1) {
            u32 add = (t + d < 256) ? sct[t + d] : 0u;
            __syncthreads();
            sct[t] += add;
            __syncthreads();
        }
        u32 incl = sct[t];
        u32 excl = incl - ctt;
        if ((int)excl < krem && (int)incl >= krem) {
            u32 run = excl;
            int bsel = 0; u32 csel = 0;
            for (int j = 15; j >= 0; --j) {
                u32 c = lh[t * 16 + j];
                run += c;
                if ((int)run >= krem) { bsel = t * 16 + j; csel = c; break; }
            }
            int newk = krem - (int)(run - csel);
            st->prefix = pref | ((u64)bsel << dsh);
            st->krem = newk;
        }
    }
}

__global__ void select_k(const u64* __restrict__ key, SelState* st,
        int2* __restrict__ pinfo, int* __restrict__ n2o) {
    int i = blockIdx.x * blockDim.x + threadIdx.x;
    if (i >= N_NODES) return;
    if (key[i] >= st->prefix) {
        int pos = atomicAdd(&st->cnt, 1);
        pinfo[i].x = pos;
        n2o[pos] = i;
    } else {
        pinfo[i].x = -1;
    }
}

// fused hp (gate-scaled features) + pooled degree + dinvp + pinfo.dv; wave per k
__global__ __launch_bounds__(256) void hp_pool_k(const float* __restrict__ h2,
        const float* __restrict__ score, const int* __restrict__ n2o,
        const int* __restrict__ rowptr, const int* __restrict__ csr,
        int2* __restrict__ pinfo, float* __restrict__ dinvp, float* __restrict__ hp) {
    int k = blockIdx.x * 4 + (threadIdx.x >> 6);
    if (k >= KSEL) return;
    int lane = threadIdx.x & 63;
    int old = n2o[k];
    float tv = tanhf(score[old]);
    const float* row = h2 + (size_t)old * HDIM;
    hp[(size_t)k * HDIM + lane]      = fmaxf(row[lane], 0.f) * tv;
    hp[(size_t)k * HDIM + lane + 64] = fmaxf(row[lane+64], 0.f) * tv;
    int rs = rowptr[old], re = rowptr[old + 1];
    int cnt = 0;
    for (int base = rs; base < re; base += 64) {
        int span = min(64, re - base);
        bool sel = false;
        if (lane < span) sel = (pinfo[csr[base + lane]].x >= 0);
        cnt += __popcll(__ballot(sel));
    }
    if (lane == 0) {
        float dv = rsqrtf((float)cnt + 1.0f);
        dinvp[k] = dv;
        pinfo[old].y = __float_as_int(dv);
    }
}

__global__ __launch_bounds__(256) void pool_stage1_k(const float* __restrict__ h,
        const int* __restrict__ n2o, const int* __restrict__ batch,
        float* __restrict__ partial, int* __restrict__ pcnt) {
    __shared__ float ls[NBATCH * HDIM];
    __shared__ int   lc[NBATCH];
    int t = threadIdx.x;
    for (int i = t; i < NBATCH * HDIM; i += 256) ls[i] = 0.0f;
    if (t < NBATCH) lc[t] = 0;
    __syncthreads();
    int wid = t >> 6, lane = t & 63;
    int start = blockIdx.x * POOL_CHUNK;
    int end = min(start + POOL_CHUNK, KSEL);
    for (int k = start + wid; k < end; k += 4) {
        int b = batch[n2o[k]];
        float2 hv = *(const float2*)&h[(size_t)k * HDIM + 2*lane];
        atomicAdd(&ls[b * HDIM + 2*lane],     fmaxf(hv.x, 0.0f));
        atomicAdd(&ls[b * HDIM + 2*lane + 1], fmaxf(hv.y, 0.0f));
        if (lane == 0) atomicAdd(&lc[b], 1);
    }
    __syncthreads();
    float* pb = partial + (size_t)blockIdx.x * (NBATCH * HDIM);
    for (int i = t; i < NBATCH * HDIM; i += 256) pb[i] = ls[i];
    if (t < NBATCH) pcnt[blockIdx.x * NBATCH + t] = lc[t];
}

__global__ __launch_bounds__(256) void pool_stage2_k(const float* __restrict__ partial,
        const int* __restrict__ pcnt, float* __restrict__ sums, float* __restrict__ cntb) {
    int i = blockIdx.x * 256 + threadIdx.x;
    if (i >= NBATCH * HDIM) return;
    float s = 0.0f;
    for (int p = 0; p < POOL_BLOCKS; ++p) s += partial[(size_t)p * NBATCH * HDIM + i];
    sums[i] = s;
    if (i < NBATCH) {
        int c = 0;
        for (int p = 0; p < POOL_BLOCKS; ++p) c += pcnt[p * NBATCH + i];
        cntb[i] = (float)c;
    }
}

// fc1 (grid) + fc2/log_softmax (last block)
__global__ __launch_bounds__(256) void fc_k(const float* __restrict__ sums,
        const float* __restrict__ cntb, const float* __restrict__ W1b,
        const float* __restrict__ b1b, const float* __restrict__ W2b,
        const float* __restrict__ b2b, float* __restrict__ gbuf,
        float* __restrict__ out, int* done) {
    int t = threadIdx.x;
    int gid = blockIdx.x * 256 + t;
    if (gid < NBATCH * HDIM) {
        int b = gid >> 7, j = gid & 127;
        float inv = 1.0f / fmaxf(cntb[b], 1.0f);
        float acc = 0.0f;
        for (int k = 0; k < HDIM; ++k) acc += sums[b * HDIM + k] * W1b[k * HDIM + j];
        gbuf[gid] = fmaxf(acc * inv + b1b[j], 0.0f);
    }
    __threadfence();
    __shared__ int lastf;
    if (t == 0) lastf = (atomicAdd(done, 1) == (int)gridDim.x - 1) ? 1 : 0;
    __syncthreads();
    if (!lastf || t >= NBATCH) return;
    __threadfence();
    int b = t;
    float l[NCLS];
    for (int c = 0; c < NCLS; ++c) {
        float acc = b2b[c];
        for (int k = 0; k < HDIM; ++k) acc += gbuf[b * HDIM + k] * W2b[k * NCLS + c];
        l[c] = acc;
    }
    float m = fmaxf(l[0], fmaxf(l[1], l[2]));
    float sum = expf(l[0]-m) + expf(l[1]-m) + expf(l[2]-m);
    float ls = logf(sum);
    for (int c = 0; c < NCLS; ++c) out[b * NCLS + c] = l[c] - m - ls;
}

extern "C" void kernel_launch(void* const* d_in, const int* in_sizes, int n_in,
                              void* d_out, int out_size, void* d_ws, size_t ws_size,
                              hipStream_t stream) {
    const float* x    = (const float*)d_in[0];
    const int*   ei   = (const int*)d_in[1];
    const int*   batch= (const int*)d_in[2];
    const float* W1   = (const float*)d_in[3];
    const float* b1   = (const float*)d_in[4];
    const float* W2   = (const float*)d_in[5];
    const float* b2   = (const float*)d_in[6];
    const float* p    = (const float*)d_in[7];
    const float* W3   = (const float*)d_in[8];
    const float* b3   = (const float*)d_in[9];
    const float* W4   = (const float*)d_in[10];
    const float* b4   = (const float*)d_in[11];
    const float* fcW1 = (const float*)d_in[12];
    const float* fcb1 = (const float*)d_in[13];
    const float* fcW2 = (const float*)d_in[14];
    const float* fcb2 = (const float*)d_in[15];
    float* out = (float*)d_out;

    char* ws = (char*)d_ws;
    size_t off = 0;
    auto alloc = [&](size_t bytes) {
        size_t r = off;
        off = (off + bytes + 255) & ~(size_t)255;
        return r;
    };
    float* A     = (float*)(ws + alloc((size_t)N_NODES * HDIM * 4));
    float* Bf    = (float*)(ws + alloc((size_t)N_NODES * HDIM * 4));
    ushort_t* Hbf= (ushort_t*)(ws + alloc((size_t)N_NODES * HDIM * 2));
    u64*   key   = (u64*)  (ws + alloc((size_t)N_NODES * 8));
    float* score = (float*)(ws + alloc((size_t)N_NODES * 4));
    int2*  pinfo = (int2*) (ws + alloc((size_t)N_NODES * 8));
    int*   n2o   = (int*)  (ws + alloc((size_t)KSEL * 4));
    float* pn    = (float*)(ws + alloc(HDIM * 4));
    float* gbuf  = (float*)(ws + alloc(NBATCH * HDIM * 4));
    SelState* st = (SelState*)(ws + alloc(256));
    float* dinv1 = (float*)(ws + alloc((size_t)N_NODES * 4));
    float* dinvp = (float*)(ws + alloc((size_t)KSEL * 4));
    int*   rowptr= (int*)  (ws + alloc((size_t)(N_NODES + 1) * 4));
    int*   csr   = (int*)  (ws + alloc((size_t)N_EDGES * 4));
    u32*   ebuf  = (u32*)  (ws + alloc((size_t)N_EDGES * 4));
    int*   bsum  = (int*)  (ws + alloc(256 * 4));
    int*   boff  = (int*)  (ws + alloc(256 * 4));
    float* partial=(float*)(ws + alloc((size_t)POOL_BLOCKS * NBATCH * HDIM * 4));
    int*   pcnt  = (int*)  (ws + alloc((size_t)POOL_BLOCKS * NBATCH * 4));
    float* sums  = (float*)(ws + alloc(NBATCH * HDIM * 4));
    float* cntb  = (float*)(ws + alloc(NBATCH * 4));
    // zeroed region: degi, gcnt, hist, done
    size_t z1 = off;
    int*   degi  = (int*)(ws + alloc((size_t)N_NODES * 4));
    u32*   gcnt  = (u32*)(ws + alloc((size_t)NBUCK * 4));
    u32*   hist  = (u32*)(ws + alloc(4 * RBINS * 4));
    int*   done  = (int*)(ws + alloc(16 * 4));
    size_t z1e = off;

    hipMemsetAsync(ws + z1, 0, z1e - z1, stream);
    init_pnorm_k<<<1, HDIM, 0, stream>>>(p, pn, st);

    const int eg   = (N_EDGES + 255) / 256;
    const int ng   = (N_NODES + 255) / 256;
    const int mm_grid_n = (N_NODES + MMB_ROWS - 1) / MMB_ROWS;
    const int mm_grid_k = (KSEL + MMB_ROWS - 1) / MMB_ROWS;
    const int gt_grid_n = (N_NODES + 3) / 4;
    const int gt_grid_k = (KSEL + 3) / 4;

    // full-graph CSR (bucketed, write-amp-free)
    deg_full_k<<<eg, 256, 0, stream>>>(ei, degi);
    scan12_k<<<ng, 256, 0, stream>>>(degi, bsum, boff, dinv1, rowptr, N_NODES, ng, done + 0);
    scan3_k<<<ng, 256, 0, stream>>>(degi, boff, rowptr, N_NODES);
    csr_bucket_k<<<S1_BLOCKS, 256, 0, stream>>>(ei, rowptr, gcnt, ebuf);
    csr_build_k<<<NBUCK, 256, 0, stream>>>(ebuf, rowptr, csr);

    // conv1: Bf = gcn(x, W1, b1)
    matmul_k<false><<<mm_grid_n, 256, 0, stream>>>(x, W1, Hbf, N_NODES);
    gather_k<false><<<gt_grid_n, 256, 0, stream>>>(rowptr, csr, dinv1, Hbf, b1, Bf,
                                                   N_NODES, nullptr, nullptr, nullptr);
    // conv2: Bf = gcn(relu(Bf), W2, b2)  + fused score/key emission
    matmul_k<true><<<mm_grid_n, 256, 0, stream>>>(Bf, W2, Hbf, N_NODES);
    gather_k<true><<<gt_grid_n, 256, 0, stream>>>(rowptr, csr, dinv1, Hbf, b2, Bf,
                                                  N_NODES, pn, score, key);

    // exact top-K: 4 x 12-bit radix passes
    for (int pass = 0; pass < 4; ++pass)
        histscan_k<<<HIST_BLOCKS, 256, 0, stream>>>(key, st, hist, pass, done + 2 + pass);
    select_k<<<ng, 256, 0, stream>>>(key, st, pinfo, n2o);

    // fused hp + pooled degrees + dinvp + pinfo.dv
    hp_pool_k<<<gt_grid_k, 256, 0, stream>>>(Bf, score, n2o, rowptr, csr, pinfo, dinvp, A);

    // conv3: Bf = gcn(hp(=A), W3, b3)
    matmul_k<false><<<mm_grid_k, 256, 0, stream>>>(A, W3, Hbf, KSEL);
    gather_pool_k<<<gt_grid_k, 256, 0, stream>>>(rowptr, csr, n2o, pinfo, dinvp, Hbf, b3, Bf);
    // conv4: A = gcn(relu(Bf), W4, b4)
    matmul_k<true><<<mm_grid_k, 256, 0, stream>>>(Bf, W4, Hbf, KSEL);
    gather_pool_k<<<gt_grid_k, 256, 0, stream>>>(rowptr, csr, n2o, pinfo, dinvp, Hbf, b4, A);

    // batch mean pool + FC head (fc2 fused as last-block)
    pool_stage1_k<<<POOL_BLOCKS, 256, 0, stream>>>(A, n2o, batch, partial, pcnt);
    pool_stage2_k<<<(NBATCH * HDIM + 255) / 256, 256, 0, stream>>>(partial, pcnt, sums, cntb);
    fc_k<<<(NBATCH * HDIM + 255) / 256, 256, 0, stream>>>(sums, cntb, fcW1, fcb1,
                                                          fcW2, fcb2, gbuf, out, done + 8);
}